// Round 2
// baseline (42108.981 us; speedup 1.0000x reference)
//
#include <hip/hip_runtime.h>
#include <hip/hip_bf16.h>
#include <cstdint>

typedef __attribute__((ext_vector_type(8))) short s8v;
typedef __attribute__((ext_vector_type(4))) float f4v;

#define DEV __device__ __forceinline__

constexpr int Hh  = 516;    // hidden per direction
constexpr int HP  = 544;    // padded hidden (17*32)
constexpr int FH  = 2064;   // 4*H
constexpr int NP  = 2176;   // 4*HP (gate-major padded)
constexpr int TT  = 512;
constexpr int BB  = 64;
constexpr int LD2 = 1088;   // padded 2H (2*HP)
constexpr int LDE = 1152;   // encpart ld (9*128)
constexpr int CS  = 528;    // c-state row stride (f32)

DEV float bf2f(unsigned short u){ return __builtin_bit_cast(float, (unsigned)u<<16); }
DEV unsigned short f2bf(float f){
  unsigned u = __builtin_bit_cast(unsigned, f);
  u += 0x7fffu + ((u>>16)&1u);
  return (unsigned short)(u>>16);
}
DEV float sigf(float x){ return 1.f/(1.f+__expf(-x)); }
DEV float tanhfast(float x){ float e=__expf(2.f*x); return 1.f - 2.f/(e+1.f); }

// ---------------- device-scope barrier (33 co-resident blocks / direction) --
DEV void gbar(unsigned* cnt, unsigned* gen, unsigned nb){
  __syncthreads();   // compiler emits s_waitcnt vmcnt(0) before s_barrier -> stores done
  if (threadIdx.x == 0) {
    __threadfence(); // agent release
    unsigned g = __hip_atomic_load(gen, __ATOMIC_RELAXED, __HIP_MEMORY_SCOPE_AGENT);
    unsigned a = __hip_atomic_fetch_add(cnt, 1u, __ATOMIC_ACQ_REL, __HIP_MEMORY_SCOPE_AGENT);
    if (a == nb-1u) {
      __hip_atomic_store(cnt, 0u, __ATOMIC_RELAXED, __HIP_MEMORY_SCOPE_AGENT);
      __hip_atomic_fetch_add(gen, 1u, __ATOMIC_RELEASE, __HIP_MEMORY_SCOPE_AGENT);
    } else {
      while (__hip_atomic_load(gen, __ATOMIC_ACQUIRE, __HIP_MEMORY_SCOPE_AGENT) == g)
        __builtin_amdgcn_s_sleep(1);
    }
    __threadfence(); // agent acquire side (invalidate stale lines)
  }
  __syncthreads();
}

// ---------------- LSTM cell core: gates = X1@W1^T + X2@W2^T + bias ---------
// Block: 256 thr (4 waves, wave = gate). Block covers j0..j0+15 of hidden.
// W1: [NP][ldw1], W2: [NP][HP]; rows gate-major padded (g*544+jj), k-contig.
DEV void cell_core(const unsigned short* __restrict__ X1, int ld1,
                   const unsigned short* __restrict__ W1, int ldw1, int K1,
                   const unsigned short* __restrict__ X2,   // [64][HP]
                   const unsigned short* __restrict__ W2,
                   const float* __restrict__ bias,          // [FH] orig gate-major
                   float* __restrict__ cst,                 // [64][CS]
                   unsigned short* __restrict__ hout,       // [64][HP]
                   unsigned short* __restrict__ yout, int ldy, int ycol,
                   int j0)
{
  const int tid = threadIdx.x;
  const int w = tid>>6, lane = tid&63, p = lane&15, q = lane>>4;
  f4v acc[4] = {};
  if (X1) {
    const unsigned short* wrow = W1 + (size_t)(w*HP + j0 + p)*ldw1 + q*8;
    for (int kk = 0; kk < (K1>>5); ++kk) {
      s8v bfr = *(const s8v*)(wrow + kk*32);
      #pragma unroll
      for (int m = 0; m < 4; ++m) {
        s8v afr = *(const s8v*)(X1 + (size_t)(m*16+p)*ld1 + kk*32 + q*8);
        acc[m] = __builtin_amdgcn_mfma_f32_16x16x32_bf16(afr, bfr, acc[m], 0, 0, 0);
      }
    }
  }
  {
    const unsigned short* wrow = W2 + (size_t)(w*HP + j0 + p)*HP + q*8;
    #pragma unroll
    for (int kk = 0; kk < HP/32; ++kk) {
      s8v bfr = *(const s8v*)(wrow + kk*32);
      #pragma unroll
      for (int m = 0; m < 4; ++m) {
        s8v afr = *(const s8v*)(X2 + (size_t)(m*16+p)*HP + kk*32 + q*8);
        acc[m] = __builtin_amdgcn_mfma_f32_16x16x32_bf16(afr, bfr, acc[m], 0, 0, 0);
      }
    }
  }
  __shared__ float gbuf[4][64][16];
  {
    int j = j0 + p;
    float bval = (j < Hh) ? bias[w*Hh + j] : 0.f;
    #pragma unroll
    for (int m = 0; m < 4; ++m)
      #pragma unroll
      for (int r = 0; r < 4; ++r) {
        int b = m*16 + q*4 + r;
        gbuf[w][b][p] = acc[m][r] + bval;
      }
  }
  __syncthreads();
  {
    int b = tid & 63, j4 = tid >> 6;
    #pragma unroll
    for (int ii = 0; ii < 4; ++ii) {
      int jj = j4*4 + ii;
      int jg = j0 + jj;
      float gi = gbuf[0][b][jj], gf = gbuf[1][b][jj];
      float gg = gbuf[2][b][jj], go = gbuf[3][b][jj];
      bool valid = jg < Hh;
      float c  = valid ? cst[(size_t)b*CS + jg] : 0.f;
      float c2 = sigf(gf)*c + sigf(gi)*tanhfast(gg);
      float h  = sigf(go)*tanhfast(c2);
      if (valid) cst[(size_t)b*CS + jg] = c2;
      unsigned short hb = valid ? f2bf(h) : (unsigned short)0;
      hout[(size_t)b*HP + jg] = hb;
      if (yout) yout[(size_t)b*ldy + ycol + jg] = hb;
    }
  }
  __syncthreads();
}

// ---------------- persistent encoder recurrent kernel (one layer, fused) ----
__global__ void __launch_bounds__(256) enc_rnn(
  const unsigned short* __restrict__ Wi,   // [2][NP][ldwi]
  int ldwi, int K1,
  const unsigned short* __restrict__ Xseq, // [T][64][ld1]
  int ld1,
  const unsigned short* __restrict__ Wh,   // [2][NP][HP]
  const float* __restrict__ eb,            // [2][FH]
  unsigned short* __restrict__ yout,       // [T][64][LD2]
  unsigned short* __restrict__ hbufs,      // [2 buf][2 dir][64][HP]
  float* __restrict__ cst,                 // [2 dir][64][CS]
  unsigned* bar)
{
  int d = blockIdx.x / 33, j0 = (blockIdx.x % 33) * 16;
  const unsigned short* W1 = Wi + (size_t)d*NP*ldwi;
  const unsigned short* W2 = Wh + (size_t)d*NP*HP;
  const float* bias = eb + (size_t)d*FH;
  float* cs = cst + (size_t)d*BB*CS;
  unsigned* c0 = bar + d*32; unsigned* g0 = c0 + 16;
  for (int t = 0; t < TT; ++t) {
    int tf = d ? (TT-1-t) : t;
    const unsigned short* hin = hbufs + (size_t)(((t&1)*2)+d)*BB*HP;
    unsigned short* hout      = hbufs + (size_t)((((t+1)&1)*2)+d)*BB*HP;
    cell_core(Xseq + (size_t)tf*BB*ld1, ld1, W1, ldwi, K1,
              hin, W2, bias, cs, hout,
              yout + (size_t)tf*BB*LD2, LD2, d*HP, j0);
    gbar(c0, g0, 33);
  }
}

// ---------------- decoder cell kernel (one step, both dirs) -----------------
__global__ void __launch_bounds__(256) dec_cell(
  const unsigned short* __restrict__ X1, int ld1, int K1,
  const unsigned short* __restrict__ hin_base,   // dec_h[p]  [4][64][HP]
  unsigned short* __restrict__ hout_base,        // dec_h[p2]
  int loff,
  const unsigned short* __restrict__ Wi, int ldwi,
  const unsigned short* __restrict__ Whh,
  const float* __restrict__ dbias,               // [2][FH]
  float* __restrict__ cstates,                   // [4][64][CS]
  unsigned short* __restrict__ yout, int ldy)
{
  int d = blockIdx.x / 33, j0 = (blockIdx.x % 33) * 16;
  cell_core(X1, ld1, Wi + (size_t)d*NP*ldwi, ldwi, K1,
    hin_base + (size_t)(loff+d)*BB*HP,
    Whh + (size_t)d*NP*HP,
    dbias + (size_t)d*FH,
    cstates + (size_t)(loff+d)*BB*CS,
    hout_base + (size_t)(loff+d)*BB*HP,
    yout, ldy, d*HP, j0);
}

// ---------------- big GEMM: C[M,N](bf16) = A[M,K](bf16) * W[N,K]^T (+bias) --
__global__ void __launch_bounds__(256) gemm_bt(
  const unsigned short* __restrict__ A, int lda,
  const unsigned short* __restrict__ W, int ldw,
  unsigned short* __restrict__ C, int ldc, int K,
  const float* __restrict__ bias, int nbias)
{
  __shared__ __align__(16) unsigned short As[128*72];
  __shared__ __align__(16) unsigned short Ws[128*72];
  int tid = threadIdx.x, w = tid>>6, lane = tid&63, p = lane&15, q = lane>>4;
  int wm = w & 1, wn = w >> 1;
  size_t m0 = (size_t)blockIdx.x * 128;
  int n0 = blockIdx.y * 128;
  f4v acc[4][4] = {};
  for (int k0 = 0; k0 < K; k0 += 64) {
    __syncthreads();
    #pragma unroll
    for (int i = 0; i < 4; ++i) {
      int v = tid + i*256;
      int row = v >> 3, k8 = (v & 7) * 8;
      *(s8v*)(As + row*72 + k8) = *(const s8v*)(A + (m0+row)*lda + k0 + k8);
      *(s8v*)(Ws + row*72 + k8) = *(const s8v*)(W + (size_t)(n0+row)*ldw + k0 + k8);
    }
    __syncthreads();
    #pragma unroll
    for (int kk = 0; kk < 2; ++kk) {
      s8v af[4], bf[4];
      #pragma unroll
      for (int i = 0; i < 4; ++i) {
        af[i] = *(const s8v*)(As + (wm*64 + i*16 + p)*72 + kk*32 + q*8);
        bf[i] = *(const s8v*)(Ws + (wn*64 + i*16 + p)*72 + kk*32 + q*8);
      }
      #pragma unroll
      for (int mt = 0; mt < 4; ++mt)
        #pragma unroll
        for (int nt = 0; nt < 4; ++nt)
          acc[mt][nt] = __builtin_amdgcn_mfma_f32_16x16x32_bf16(af[mt], bf[nt], acc[mt][nt], 0,0,0);
    }
  }
  #pragma unroll
  for (int mt = 0; mt < 4; ++mt)
    #pragma unroll
    for (int nt = 0; nt < 4; ++nt)
      #pragma unroll
      for (int r = 0; r < 4; ++r) {
        size_t row = m0 + wm*64 + mt*16 + q*4 + r;
        int col = n0 + wn*64 + nt*16 + p;
        float v = acc[mt][nt][r];
        if (bias && col < nbias) v += bias[col];
        C[row*ldc + col] = f2bf(v);
      }
}

// ---------------- small GEMM (M=64): C = A[64,K] * W[N,K]^T ----------------
__global__ void __launch_bounds__(256) gemm64(
  const unsigned short* __restrict__ A, int lda,
  const unsigned short* __restrict__ W, int ldw, int K,
  const float* __restrict__ bias, int nbias, int mode,  // 0:f32 1:bf16 2:bf16+tanh
  void* __restrict__ C, int ldc)
{
  int tid = threadIdx.x, w = tid>>6, lane = tid&63, p = lane&15, q = lane>>4;
  int n0 = blockIdx.x*64 + w*16;
  f4v acc[4] = {};
  const unsigned short* wrow = W + (size_t)(n0+p)*ldw + q*8;
  for (int kk = 0; kk < K/32; ++kk) {
    s8v bfr = *(const s8v*)(wrow + kk*32);
    #pragma unroll
    for (int m = 0; m < 4; ++m) {
      s8v afr = *(const s8v*)(A + (size_t)(m*16+p)*lda + kk*32 + q*8);
      acc[m] = __builtin_amdgcn_mfma_f32_16x16x32_bf16(afr, bfr, acc[m], 0,0,0);
    }
  }
  #pragma unroll
  for (int m = 0; m < 4; ++m)
    #pragma unroll
    for (int r = 0; r < 4; ++r) {
      int b = m*16 + q*4 + r, col = n0 + p;
      float v = acc[m][r];
      if (bias && col < nbias) v += bias[col];
      if (mode == 2) v = tanhfast(v);
      if (mode == 0) ((float*)C)[(size_t)b*ldc + col] = v;
      else ((unsigned short*)C)[(size_t)b*ldc + col] = f2bf(v);
    }
}

// ---------------- attention score: score[t,b] = sum_n v[n]*tanh(enc+q) ------
__global__ void __launch_bounds__(256) attn_score(
  const unsigned short* __restrict__ encp,  // [T*64][LDE] bf16 (incl attn_b)
  const float* __restrict__ qv,             // [64][LDE]
  const float* __restrict__ av,             // attn_v [1032]
  float* __restrict__ score)                // [T][64]
{
  int t = blockIdx.x;
  int w = threadIdx.x>>6, lane = threadIdx.x&63;
  float vv[17];
  #pragma unroll
  for (int i = 0; i < 17; ++i) { int n = i*64+lane; vv[i] = (n < 1032) ? av[n] : 0.f; }
  const unsigned short* erow = encp + (size_t)t*BB*LDE;
  for (int bb = 0; bb < 16; ++bb) {
    int b = w*16 + bb;
    const unsigned short* e = erow + (size_t)b*LDE;
    const float* qb = qv + (size_t)b*LDE;
    float s = 0.f;
    #pragma unroll
    for (int i = 0; i < 17; ++i) {
      int n = i*64 + lane;
      s += vv[i] * tanhfast(bf2f(e[n]) + qb[n]);
    }
    #pragma unroll
    for (int off = 32; off; off >>= 1) s += __shfl_xor(s, off);
    if (lane == 0) score[(size_t)t*BB + b] = s;
  }
}

// ---------------- softmax over T + context; writes context into Xc ---------
__global__ void __launch_bounds__(256) attn_ctx(
  const float* __restrict__ score,          // [T][64]
  const unsigned short* __restrict__ outenc,// [T*64][LD2]
  unsigned short* __restrict__ Xc)          // [64][2176], context at cols 1088+
{
  __shared__ float aw[512];
  __shared__ float red[4];
  int tid = threadIdx.x, w = tid>>6, lane = tid&63;
  int b = blockIdx.x >> 1, half = blockIdx.x & 1;
  float s0 = score[(size_t)tid*BB + b];
  float s1 = score[(size_t)(tid+256)*BB + b];
  float m = fmaxf(s0, s1);
  #pragma unroll
  for (int off = 32; off; off >>= 1) m = fmaxf(m, __shfl_xor(m, off));
  if (lane == 0) red[w] = m;
  __syncthreads();
  m = fmaxf(fmaxf(red[0], red[1]), fmaxf(red[2], red[3]));
  __syncthreads();
  float e0 = __expf(s0 - m), e1 = __expf(s1 - m);
  aw[tid] = e0; aw[tid+256] = e1;
  float ss = e0 + e1;
  #pragma unroll
  for (int off = 32; off; off >>= 1) ss += __shfl_xor(ss, off);
  if (lane == 0) red[w] = ss;
  __syncthreads();
  float inv = 1.f / (red[0]+red[1]+red[2]+red[3]);
  float acc0 = 0.f, acc1 = 0.f, acc2 = 0.f;
  const unsigned short* base = outenc + (size_t)b*LD2 + half*HP;
  for (int t = 0; t < 512; ++t) {
    float a_ = aw[t];
    const unsigned short* orow = base + (size_t)t*BB*LD2;
    acc0 += a_ * bf2f(orow[tid]);
    acc1 += a_ * bf2f(orow[tid+256]);
    if (tid < 32) acc2 += a_ * bf2f(orow[tid+512]);
  }
  unsigned short* dst = Xc + (size_t)b*2176 + 1088 + half*HP;
  dst[tid]      = f2bf(acc0*inv);
  dst[tid+256]  = f2bf(acc1*inv);
  if (tid < 32) dst[tid+512] = f2bf(acc2*inv);
}

// ---------------- cross-entropy for one decoder step ------------------------
__global__ void ce_k(const float* __restrict__ logits, // [64][64] f32, 20 valid
                     const int* __restrict__ label,    // [64]
                     float* __restrict__ out)
{
  int b = threadIdx.x; // 64 threads = 1 wave
  const float* lr = logits + (size_t)b*64;
  float m = -1e30f;
  for (int n = 0; n < 20; ++n) m = fmaxf(m, lr[n]);
  float s = 0.f;
  for (int n = 0; n < 20; ++n) s += __expf(lr[n] - m);
  int li = label[b];
  float ce = -(lr[li] - m - __logf(s));
  #pragma unroll
  for (int off = 32; off; off >>= 1) ce += __shfl_xor(ce, off);
  if (b == 0) atomicAdd(out, ce * (1.f/64.f));
}

// ---------------- expand: xe = x @ expand_W^T + expand_b --------------------
__global__ void __launch_bounds__(256) expand_k(
  const float* __restrict__ x, const float* __restrict__ eW,
  const float* __restrict__ ebi, unsigned short* __restrict__ xe)
{
  int row = blockIdx.x, j = threadIdx.x;
  const float* xr = x + (size_t)row*4;
  float4 wv = ((const float4*)eW)[j];
  float v = ebi[j] + xr[0]*wv.x + xr[1]*wv.y + xr[2]*wv.z + xr[3]*wv.w;
  xe[(size_t)row*256 + j] = f2bf(v);
}

// ---------------- decoder state init from encoder finals --------------------
__global__ void __launch_bounds__(256) dec_init(
  const unsigned short* __restrict__ encH,  // [2 layer][2 buf][2 dir][64][HP]
  const float* __restrict__ encC,           // [2 layer][2 dir][64][CS]
  unsigned short* __restrict__ decH,        // parity0: [4][64][HP]
  float* __restrict__ decC)                 // [4][64][CS]
{
  int tid = blockIdx.x*256 + threadIdx.x;
  int nth = gridDim.x*256;
  for (int i = tid; i < 4*BB*HP; i += nth) {
    int k = i / (BB*HP), rem = i % (BB*HP);
    decH[i] = encH[((size_t)(k>>1)*4 + (k&1))*BB*HP + rem]; // buf0
  }
  for (int i = tid; i < 4*BB*CS; i += nth) {
    int k = i / (BB*CS), rem = i % (BB*CS);
    decC[i] = encC[((size_t)(k>>1)*2 + (k&1))*BB*CS + rem];
  }
}

// ---------------- weight prepack (f32 -> padded bf16) -----------------------
struct PackA {
  const float *eWi0,*eWh0,*eWi1,*eWh1,*dWi0,*dWh0,*dWi1,*dWh1,*aW,*cW,*oW,*y;
  unsigned short *pEWi0,*pEWh0,*pEWi1,*pEWh1,*pDWi0,*pDWh0,*pDWi1,*pDWh1,
                 *pAW1,*pAW2,*pCW,*pOW,*pY;
};

__global__ void __launch_bounds__(256) pack_k(PackA a){
  int job = blockIdx.y, row = blockIdx.x, tid = threadIdx.x;
  if (job < 16) {
    if (row >= NP) return;
    int d = job & 1, jt = job >> 1;
    int g = row / HP, jj = row % HP; bool vr = jj < Hh; int sr = g*Hh + jj;
    if (jt == 0) {
      unsigned short* dst = a.pEWi0 + ((size_t)d*NP + row)*256;
      const float* s = a.eWi0 + ((size_t)d*FH + sr)*256;
      for (int k = tid; k < 256; k += 256) dst[k] = vr ? f2bf(s[k]) : 0;
    } else if (jt == 1) {
      unsigned short* dst = a.pEWh0 + ((size_t)d*NP + row)*HP;
      const float* s = a.eWh0 + ((size_t)d*FH + sr)*Hh;
      for (int k = tid; k < HP; k += 256) dst[k] = (vr && k < Hh) ? f2bf(s[k]) : 0;
    } else if (jt == 2) {
      unsigned short* dst = a.pEWi1 + ((size_t)d*NP + row)*LD2;
      const float* s = a.eWi1 + ((size_t)d*FH + sr)*1032;
      for (int k = tid; k < LD2; k += 256) {
        int d2 = k/HP, j = k%HP;
        dst[k] = (vr && j < Hh) ? f2bf(s[d2*Hh + j]) : 0;
      }
    } else if (jt == 3) {
      unsigned short* dst = a.pEWh1 + ((size_t)d*NP + row)*HP;
      const float* s = a.eWh1 + ((size_t)d*FH + sr)*Hh;
      for (int k = tid; k < HP; k += 256) dst[k] = (vr && k < Hh) ? f2bf(s[k]) : 0;
    } else if (jt == 4) {
      unsigned short* dst = a.pDWi0 + ((size_t)d*NP + row)*64;
      const float* s = a.dWi0 + ((size_t)d*FH + sr)*20;
      for (int k = tid; k < 64; k += 256) dst[k] = (vr && k < 20) ? f2bf(s[k]) : 0;
    } else if (jt == 5) {
      unsigned short* dst = a.pDWh0 + ((size_t)d*NP + row)*HP;
      const float* s = a.dWh0 + ((size_t)d*FH + sr)*Hh;
      for (int k = tid; k < HP; k += 256) dst[k] = (vr && k < Hh) ? f2bf(s[k]) : 0;
    } else if (jt == 6) {
      unsigned short* dst = a.pDWi1 + ((size_t)d*NP + row)*LD2;
      const float* s = a.dWi1 + ((size_t)d*FH + sr)*1032;
      for (int k = tid; k < LD2; k += 256) {
        int d2 = k/HP, j = k%HP;
        dst[k] = (vr && j < Hh) ? f2bf(s[d2*Hh + j]) : 0;
      }
    } else {
      unsigned short* dst = a.pDWh1 + ((size_t)d*NP + row)*HP;
      const float* s = a.dWh1 + ((size_t)d*FH + sr)*Hh;
      for (int k = tid; k < HP; k += 256) dst[k] = (vr && k < Hh) ? f2bf(s[k]) : 0;
    }
  } else if (job == 16 || job == 17) {
    if (row >= LDE) return;
    bool vr = row < 1032;
    unsigned short* dst = (job == 16 ? a.pAW1 : a.pAW2) + (size_t)row*LD2;
    int off = (job == 16 ? 0 : 1032);
    for (int k = tid; k < LD2; k += 256) {
      int d2 = k/HP, j = k%HP;
      dst[k] = (vr && j < Hh) ? f2bf(a.aW[(size_t)row*FH + off + d2*Hh + j]) : 0;
    }
  } else if (job == 18) {
    if (row >= LDE) return;
    bool vr = row < 1032;
    unsigned short* dst = a.pCW + (size_t)row*2176;
    for (int k = tid; k < 2176; k += 256) {
      int half = k/LD2, r2 = k%LD2, d2 = r2/HP, j = r2%HP;
      dst[k] = (vr && j < Hh) ? f2bf(a.cW[(size_t)row*FH + half*1032 + d2*Hh + j]) : 0;
    }
  } else if (job == 19) {
    if (row >= 64) return;
    unsigned short* dst = a.pOW + (size_t)row*LD2;
    for (int k = tid; k < LD2; k += 256)
      dst[k] = (row < 20 && k < 1032) ? f2bf(a.oW[(size_t)row*1032 + k]) : 0;
  } else {
    if (row >= 1280) return;
    unsigned short* dst = a.pY + (size_t)row*64;
    for (int k = tid; k < 64; k += 256)
      dst[k] = (k < 20) ? f2bf(a.y[(size_t)row*20 + k]) : 0;
  }
}

// ======================== host side =========================================
extern "C" void kernel_launch(void* const* d_in, const int* in_sizes, int n_in,
                              void* d_out, int out_size, void* d_ws, size_t ws_size,
                              hipStream_t stream) {
  const float* x    = (const float*)d_in[0];
  const float* y    = (const float*)d_in[1];
  const int* label  = (const int*)d_in[2];
  const float* expW = (const float*)d_in[3];
  const float* expb = (const float*)d_in[4];
  const float* eWi0 = (const float*)d_in[5];
  const float* eWh0 = (const float*)d_in[6];
  const float* eb0  = (const float*)d_in[7];
  const float* eWi1 = (const float*)d_in[8];
  const float* eWh1 = (const float*)d_in[9];
  const float* eb1  = (const float*)d_in[10];
  const float* dWi0 = (const float*)d_in[11];
  const float* dWh0 = (const float*)d_in[12];
  const float* db0  = (const float*)d_in[13];
  const float* dWi1 = (const float*)d_in[14];
  const float* dWh1 = (const float*)d_in[15];
  const float* db1  = (const float*)d_in[16];
  const float* attW = (const float*)d_in[17];
  const float* attb = (const float*)d_in[18];
  const float* attv = (const float*)d_in[19];
  const float* cW   = (const float*)d_in[20];
  const float* cb   = (const float*)d_in[21];
  const float* oW   = (const float*)d_in[22];
  const float* ob   = (const float*)d_in[23];

  char* base = (char*)d_ws;
  size_t o = 0;
  auto alloc = [&](size_t bytes){ size_t r = o; o = (o + bytes + 255) & ~(size_t)255; return r; };

  // --- zero region (small state) ---
  size_t o_encH  = alloc((size_t)2*2*2*BB*HP*2);
  size_t o_decH  = alloc((size_t)2*4*BB*HP*2);
  size_t o_l0    = alloc((size_t)BB*LD2*2);
  size_t o_Xc    = alloc((size_t)BB*2176*2);
  size_t o_encC  = alloc((size_t)2*2*BB*CS*4);
  size_t o_decC  = alloc((size_t)4*BB*CS*4);
  size_t o_bar   = alloc(256);
  size_t ZB = o;
  // --- rest ---
  size_t o_xe    = alloc((size_t)TT*BB*256*2);
  size_t o_big   = alloc((size_t)TT*BB*LDE*2);   // y0 during enc; encp after
  size_t o_oenc  = alloc((size_t)TT*BB*LD2*2);
  size_t o_pEWi0 = alloc((size_t)2*NP*256*2);
  size_t o_pEWh0 = alloc((size_t)2*NP*HP*2);
  size_t o_pEWi1 = alloc((size_t)2*NP*LD2*2);
  size_t o_pEWh1 = alloc((size_t)2*NP*HP*2);
  size_t o_pDWi0 = alloc((size_t)2*NP*64*2);
  size_t o_pDWh0 = alloc((size_t)2*NP*HP*2);
  size_t o_pDWi1 = alloc((size_t)2*NP*LD2*2);
  size_t o_pDWh1 = alloc((size_t)2*NP*HP*2);
  size_t o_pAW1  = alloc((size_t)LDE*LD2*2);
  size_t o_pAW2  = alloc((size_t)LDE*LD2*2);
  size_t o_pCW   = alloc((size_t)LDE*2176*2);
  size_t o_pOW   = alloc((size_t)64*LD2*2);
  size_t o_pY    = alloc((size_t)1280*64*2);
  size_t o_q     = alloc((size_t)BB*LDE*4);
  size_t o_score = alloc((size_t)TT*BB*4);
  size_t o_co    = alloc((size_t)BB*LD2*2);
  size_t o_log   = alloc((size_t)BB*64*4);
  (void)in_sizes; (void)n_in; (void)out_size;

  if (o > ws_size) return;   // diagnostic guard: too-small workspace -> clean absmax fail

  unsigned short* encH = (unsigned short*)(base + o_encH);
  unsigned short* decH = (unsigned short*)(base + o_decH);
  unsigned short* l0   = (unsigned short*)(base + o_l0);
  unsigned short* Xc   = (unsigned short*)(base + o_Xc);
  float* encC = (float*)(base + o_encC);
  float* decC = (float*)(base + o_decC);
  unsigned* bar = (unsigned*)(base + o_bar);
  unsigned short* xe   = (unsigned short*)(base + o_xe);
  unsigned short* y0   = (unsigned short*)(base + o_big);   // [T][64][LD2]
  unsigned short* encp = (unsigned short*)(base + o_big);   // [T][64][LDE] (after y0 dead)
  unsigned short* oenc = (unsigned short*)(base + o_oenc);
  unsigned short* pEWi0 = (unsigned short*)(base + o_pEWi0);
  unsigned short* pEWh0 = (unsigned short*)(base + o_pEWh0);
  unsigned short* pEWi1 = (unsigned short*)(base + o_pEWi1);
  unsigned short* pEWh1 = (unsigned short*)(base + o_pEWh1);
  unsigned short* pDWi0 = (unsigned short*)(base + o_pDWi0);
  unsigned short* pDWh0 = (unsigned short*)(base + o_pDWh0);
  unsigned short* pDWi1 = (unsigned short*)(base + o_pDWi1);
  unsigned short* pDWh1 = (unsigned short*)(base + o_pDWh1);
  unsigned short* pAW1 = (unsigned short*)(base + o_pAW1);
  unsigned short* pAW2 = (unsigned short*)(base + o_pAW2);
  unsigned short* pCW  = (unsigned short*)(base + o_pCW);
  unsigned short* pOW  = (unsigned short*)(base + o_pOW);
  unsigned short* pY   = (unsigned short*)(base + o_pY);
  float* qbuf  = (float*)(base + o_q);
  float* score = (float*)(base + o_score);
  unsigned short* co = (unsigned short*)(base + o_co);
  float* logits = (float*)(base + o_log);

  hipMemsetAsync(d_ws, 0, ZB, stream);
  hipMemsetAsync(d_out, 0, sizeof(float), stream);

  PackA pa;
  pa.eWi0 = eWi0; pa.eWh0 = eWh0; pa.eWi1 = eWi1; pa.eWh1 = eWh1;
  pa.dWi0 = dWi0; pa.dWh0 = dWh0; pa.dWi1 = dWi1; pa.dWh1 = dWh1;
  pa.aW = attW; pa.cW = cW; pa.oW = oW; pa.y = y;
  pa.pEWi0 = pEWi0; pa.pEWh0 = pEWh0; pa.pEWi1 = pEWi1; pa.pEWh1 = pEWh1;
  pa.pDWi0 = pDWi0; pa.pDWh0 = pDWh0; pa.pDWi1 = pDWi1; pa.pDWh1 = pDWh1;
  pa.pAW1 = pAW1; pa.pAW2 = pAW2; pa.pCW = pCW; pa.pOW = pOW; pa.pY = pY;
  pack_k<<<dim3(NP, 21), 256, 0, stream>>>(pa);

  expand_k<<<TT*BB, 256, 0, stream>>>(x, expW, expb, xe);

  // encoder layer 0 (fused input GEMM + recurrence)
  enc_rnn<<<66, 256, 0, stream>>>(pEWi0, 256, 256, xe, 256,
      pEWh0, eb0, y0, encH, encC, bar);
  // encoder layer 1
  enc_rnn<<<66, 256, 0, stream>>>(pEWi1, LD2, LD2, y0, LD2,
      pEWh1, eb1, oenc, encH + (size_t)2*2*BB*HP, encC + (size_t)2*BB*CS, bar);

  dec_init<<<64, 256, 0, stream>>>(encH, encC, decH, decC);

  // enc_part = outenc @ attn_W[:,1032:]^T + attn_b   (y0 dead -> encp aliases it)
  gemm_bt<<<dim3(256, 9), 256, 0, stream>>>(
      oenc, LD2, pAW2, LD2, encp, LDE, LD2, attb, 1032);

  const size_t DHB = (size_t)4*BB*HP;
  for (int s = 0; s < 20; ++s) {
    int p = s & 1, p2 = p ^ 1;
    dec_cell<<<66, 256, 0, stream>>>(
      pY + (size_t)s*64*64, 64, 64, decH + (size_t)p*DHB, decH + (size_t)p2*DHB, 0,
      pDWi0, 64, pDWh0, db0, decC, l0, LD2);
    dec_cell<<<66, 256, 0, stream>>>(
      l0, LD2, LD2, decH + (size_t)p*DHB, decH + (size_t)p2*DHB, 2,
      pDWi1, LD2, pDWh1, db1, decC, Xc, 2176);
    gemm64<<<18, 256, 0, stream>>>(Xc, 2176, pAW1, LD2, LD2, nullptr, 0, 0, qbuf, LDE);
    attn_score<<<512, 256, 0, stream>>>(encp, qbuf, attv, score);
    attn_ctx<<<128, 256, 0, stream>>>(score, oenc, Xc);
    gemm64<<<17, 256, 0, stream>>>(Xc, 2176, pCW, 2176, 2176, cb, 1032, 2, co, LD2);
    gemm64<<<1, 256, 0, stream>>>(co, LD2, pOW, LD2, LD2, ob, 20, 0, logits, 64);
    ce_k<<<1, 64, 0, stream>>>(logits, label + (size_t)s*64, (float*)d_out);
  }
}

// Round 3
// 26523.871 us; speedup vs baseline: 1.5876x; 1.5876x over previous
//
#include <hip/hip_runtime.h>
#include <hip/hip_bf16.h>
#include <cstdint>

typedef __attribute__((ext_vector_type(8))) short s8v;
typedef __attribute__((ext_vector_type(4))) float f4v;

#define DEV __device__ __forceinline__

constexpr int Hh  = 516;    // hidden per direction
constexpr int HP  = 544;    // padded hidden (17*32)
constexpr int FH  = 2064;   // 4*H
constexpr int NP  = 2176;   // 4*HP (gate-major padded)
constexpr int TT  = 512;
constexpr int BB  = 64;
constexpr int LD2 = 1088;   // padded 2H (2*HP)
constexpr int LDE = 1152;   // encpart ld (9*128)
constexpr int CS  = 528;    // c-state row stride (f32)
constexpr int XR  = 584;    // LDS stage row stride (shorts); ≡8 mod 64 → p*4 bank pattern

DEV float bf2f(unsigned short u){ return __builtin_bit_cast(float, (unsigned)u<<16); }
DEV unsigned short f2bf(float f){
  unsigned u = __builtin_bit_cast(unsigned, f);
  u += 0x7fffu + ((u>>16)&1u);
  return (unsigned short)(u>>16);
}
DEV float sigf(float x){ return 1.f/(1.f+__expf(-x)); }
DEV float tanhfast(float x){ float e=__expf(2.f*x); return 1.f - 2.f/(e+1.f); }

DEV __attribute__((always_inline))
unsigned long long aload(const unsigned long long* p){
  return __hip_atomic_load(p, __ATOMIC_RELAXED, __HIP_MEMORY_SCOPE_AGENT);
}

// ---------------- X1 (input-side) MFMAs, direct global (cached, L2-hot) -----
DEV void cell_x1(f4v (&acc)[4],
                 const unsigned short* __restrict__ X1, int ld1,
                 const unsigned short* __restrict__ W1, int ldw1, int K1,
                 int j0)
{
  const int tid = threadIdx.x;
  const int w = tid>>6, lane = tid&63, p = lane&15, q = lane>>4;
  const unsigned short* wrow = W1 + (size_t)(w*HP + j0 + p)*ldw1 + q*8;
  for (int kk = 0; kk < (K1>>5); ++kk) {
    s8v bfr = *(const s8v*)(wrow + (size_t)kk*32);
    #pragma unroll
    for (int m = 0; m < 4; ++m) {
      s8v afr = *(const s8v*)(X1 + (size_t)(m*16+p)*ld1 + kk*32 + q*8);
      acc[m] = __builtin_amdgcn_mfma_f32_16x16x32_bf16(afr, bfr, acc[m], 0, 0, 0);
    }
  }
}

// ---------------- h-side MFMAs (X2 staged via LDS) + gate epilogue ---------
// BYP: X2 global reads as relaxed device-scope atomics (IF-coherent, no fences)
template<bool BYP>
DEV void cell_rest(f4v (&acc)[4],
                   const unsigned short* __restrict__ X2g,  // [64][HP]
                   const unsigned short* __restrict__ W2,   // [NP][HP]
                   const float* __restrict__ bias,          // [FH] gate-major
                   float* __restrict__ cst,                 // [64][CS]
                   unsigned* __restrict__ hout,             // [64][HP/2] packed
                   unsigned short* __restrict__ yout, int ldy, int ycol,
                   int j0)
{
  __shared__ __align__(16) unsigned short Xs[64*XR];
  __shared__ float gbuf[4][64][17];
  const int tid = threadIdx.x;
  const int w = tid>>6, lane = tid&63, p = lane&15, q = lane>>4;

  // ---- stage X2 -> LDS (each byte loaded once per block) ----
  {
    int row = tid >> 2, c4 = (tid & 3) * 4;   // 8B per thread per iter
    unsigned long long tmp[34];
    #pragma unroll
    for (int it = 0; it < 34; ++it) {
      const unsigned long long* s =
        (const unsigned long long*)(X2g + (size_t)row*HP + it*16 + c4);
      tmp[it] = BYP ? aload(s) : *s;
    }
    #pragma unroll
    for (int it = 0; it < 34; ++it)
      *(unsigned long long*)(Xs + row*XR + it*16 + c4) = tmp[it];
  }
  __syncthreads();

  // ---- h-side MFMAs from LDS ----
  {
    const unsigned short* wrow = W2 + (size_t)(w*HP + j0 + p)*HP + q*8;
    #pragma unroll
    for (int kk = 0; kk < HP/32; ++kk) {
      s8v bfr = *(const s8v*)(wrow + kk*32);
      #pragma unroll
      for (int m = 0; m < 4; ++m) {
        s8v afr = *(const s8v*)(Xs + (m*16+p)*XR + kk*32 + q*8);
        acc[m] = __builtin_amdgcn_mfma_f32_16x16x32_bf16(afr, bfr, acc[m], 0, 0, 0);
      }
    }
  }
  // ---- gates -> LDS (padded, conflict-free) ----
  {
    int j = j0 + p;
    float bval = (j < Hh) ? bias[w*Hh + j] : 0.f;
    #pragma unroll
    for (int m = 0; m < 4; ++m)
      #pragma unroll
      for (int r = 0; r < 4; ++r)
        gbuf[w][m*16 + q*4 + r][p] = acc[m][r] + bval;
  }
  __syncthreads();
  // ---- cell nonlinearity + packed state/output writes ----
  {
    int b = tid & 63, j4 = tid >> 6;
    unsigned short hb[4];
    #pragma unroll
    for (int ii = 0; ii < 4; ++ii) {
      int jj = j4*4 + ii, jg = j0 + jj;
      float gi = gbuf[0][b][jj], gf = gbuf[1][b][jj];
      float gg = gbuf[2][b][jj], go = gbuf[3][b][jj];
      bool valid = jg < Hh;
      float c  = valid ? cst[(size_t)b*CS + jg] : 0.f;
      float c2 = sigf(gf)*c + sigf(gi)*tanhfast(gg);
      float h  = sigf(go)*tanhfast(c2);
      if (valid) cst[(size_t)b*CS + jg] = c2;
      hb[ii] = valid ? f2bf(h) : (unsigned short)0;
    }
    unsigned hu0 = (unsigned)hb[0] | ((unsigned)hb[1] << 16);
    unsigned hu1 = (unsigned)hb[2] | ((unsigned)hb[3] << 16);
    unsigned* hp = hout + (size_t)b*(HP/2) + (j0 + j4*4)/2;
    __hip_atomic_store(hp,   hu0, __ATOMIC_RELAXED, __HIP_MEMORY_SCOPE_AGENT);
    __hip_atomic_store(hp+1, hu1, __ATOMIC_RELAXED, __HIP_MEMORY_SCOPE_AGENT);
    unsigned long long yv = (unsigned long long)hu0 | ((unsigned long long)hu1 << 32);
    *(unsigned long long*)(yout + (size_t)b*ldy + ycol + j0 + j4*4) = yv;
  }
  __syncthreads();   // drains vmcnt: all h atomic stores retired before flag add
}

// ---------------- persistent encoder recurrent kernel (one layer, fused) ----
__global__ void __launch_bounds__(256) enc_rnn(
  const unsigned short* __restrict__ Wi,   // [2][NP][ldwi]
  int ldwi, int K1,
  const unsigned short* __restrict__ Xseq, // [T][64][ld1]
  int ld1,
  const unsigned short* __restrict__ Wh,   // [2][NP][HP]
  const float* __restrict__ eb,            // [2][FH]
  unsigned short* __restrict__ yout,       // [T][64][LD2]
  unsigned short* __restrict__ hbufs,      // [2 buf][2 dir][64][HP]
  float* __restrict__ cst,                 // [2 dir][64][CS]
  unsigned* flags)                         // [2 dir][TT] monotonic step counters
{
  int d = blockIdx.x / 33, j0 = (blockIdx.x % 33) * 16;
  const unsigned short* W1 = Wi + (size_t)d*NP*ldwi;
  const unsigned short* W2 = Wh + (size_t)d*NP*HP;
  const float* bias = eb + (size_t)d*FH;
  float* cs = cst + (size_t)d*BB*CS;
  unsigned* flg = flags + (size_t)d*TT;
  for (int t = 0; t < TT; ++t) {
    int tf = d ? (TT-1-t) : t;
    const unsigned short* hin = hbufs + (size_t)((t&1)*2 + d)*BB*HP;
    unsigned* hout = (unsigned*)(hbufs + (size_t)(((t+1)&1)*2 + d)*BB*HP);
    f4v acc[4] = {};
    cell_x1(acc, Xseq + (size_t)tf*BB*ld1, ld1, W1, ldwi, K1, j0);
    if (t > 0 && threadIdx.x == 0) {
      while (__hip_atomic_load(flg + (t-1), __ATOMIC_RELAXED,
                               __HIP_MEMORY_SCOPE_AGENT) < 33u)
        __builtin_amdgcn_s_sleep(1);
    }
    __syncthreads();
    cell_rest<true>(acc, hin, W2, bias, cs, hout,
                    yout + (size_t)tf*BB*LD2, LD2, d*HP, j0);
    if (threadIdx.x == 0)
      __hip_atomic_fetch_add(flg + t, 1u, __ATOMIC_RELAXED, __HIP_MEMORY_SCOPE_AGENT);
  }
}

// ---------------- decoder cell kernel (one step, both dirs) -----------------
__global__ void __launch_bounds__(256) dec_cell(
  const unsigned short* __restrict__ X1, int ld1, int K1,
  const unsigned short* __restrict__ hin_base,   // dec_h[p]  [4][64][HP]
  unsigned short* __restrict__ hout_base,        // dec_h[p2]
  int loff,
  const unsigned short* __restrict__ Wi, int ldwi,
  const unsigned short* __restrict__ Whh,
  const float* __restrict__ dbias,               // [2][FH]
  float* __restrict__ cstates,                   // [4][64][CS]
  unsigned short* __restrict__ yout, int ldy)
{
  int d = blockIdx.x / 33, j0 = (blockIdx.x % 33) * 16;
  f4v acc[4] = {};
  cell_x1(acc, X1, ld1, Wi + (size_t)d*NP*ldwi, ldwi, K1, j0);
  cell_rest<false>(acc,
    hin_base + (size_t)(loff+d)*BB*HP,
    Whh + (size_t)d*NP*HP,
    dbias + (size_t)d*FH,
    cstates + (size_t)(loff+d)*BB*CS,
    (unsigned*)(hout_base + (size_t)(loff+d)*BB*HP),
    yout, ldy, d*HP, j0);
}

// ---------------- big GEMM: C[M,N](bf16) = A[M,K](bf16) * W[N,K]^T (+bias) --
__global__ void __launch_bounds__(256) gemm_bt(
  const unsigned short* __restrict__ A, int lda,
  const unsigned short* __restrict__ W, int ldw,
  unsigned short* __restrict__ C, int ldc, int K,
  const float* __restrict__ bias, int nbias)
{
  __shared__ __align__(16) unsigned short As[128*72];
  __shared__ __align__(16) unsigned short Ws[128*72];
  int tid = threadIdx.x, w = tid>>6, lane = tid&63, p = lane&15, q = lane>>4;
  int wm = w & 1, wn = w >> 1;
  size_t m0 = (size_t)blockIdx.x * 128;
  int n0 = blockIdx.y * 128;
  f4v acc[4][4] = {};
  for (int k0 = 0; k0 < K; k0 += 64) {
    __syncthreads();
    #pragma unroll
    for (int i = 0; i < 4; ++i) {
      int v = tid + i*256;
      int row = v >> 3, k8 = (v & 7) * 8;
      *(s8v*)(As + row*72 + k8) = *(const s8v*)(A + (m0+row)*lda + k0 + k8);
      *(s8v*)(Ws + row*72 + k8) = *(const s8v*)(W + (size_t)(n0+row)*ldw + k0 + k8);
    }
    __syncthreads();
    #pragma unroll
    for (int kk = 0; kk < 2; ++kk) {
      s8v af[4], bf[4];
      #pragma unroll
      for (int i = 0; i < 4; ++i) {
        af[i] = *(const s8v*)(As + (wm*64 + i*16 + p)*72 + kk*32 + q*8);
        bf[i] = *(const s8v*)(Ws + (wn*64 + i*16 + p)*72 + kk*32 + q*8);
      }
      #pragma unroll
      for (int mt = 0; mt < 4; ++mt)
        #pragma unroll
        for (int nt = 0; nt < 4; ++nt)
          acc[mt][nt] = __builtin_amdgcn_mfma_f32_16x16x32_bf16(af[mt], bf[nt], acc[mt][nt], 0,0,0);
    }
  }
  #pragma unroll
  for (int mt = 0; mt < 4; ++mt)
    #pragma unroll
    for (int nt = 0; nt < 4; ++nt)
      #pragma unroll
      for (int r = 0; r < 4; ++r) {
        size_t row = m0 + wm*64 + mt*16 + q*4 + r;
        int col = n0 + wn*64 + nt*16 + p;
        float v = acc[mt][nt][r];
        if (bias && col < nbias) v += bias[col];
        C[row*ldc + col] = f2bf(v);
      }
}

// ---------------- small GEMM (M=64): C = A[64,K] * W[N,K]^T ----------------
__global__ void __launch_bounds__(256) gemm64(
  const unsigned short* __restrict__ A, int lda,
  const unsigned short* __restrict__ W, int ldw, int K,
  const float* __restrict__ bias, int nbias, int mode,  // 0:f32 1:bf16 2:bf16+tanh
  void* __restrict__ C, int ldc)
{
  int tid = threadIdx.x, w = tid>>6, lane = tid&63, p = lane&15, q = lane>>4;
  int n0 = blockIdx.x*64 + w*16;
  f4v acc[4] = {};
  const unsigned short* wrow = W + (size_t)(n0+p)*ldw + q*8;
  for (int kk = 0; kk < K/32; ++kk) {
    s8v bfr = *(const s8v*)(wrow + kk*32);
    #pragma unroll
    for (int m = 0; m < 4; ++m) {
      s8v afr = *(const s8v*)(A + (size_t)(m*16+p)*lda + kk*32 + q*8);
      acc[m] = __builtin_amdgcn_mfma_f32_16x16x32_bf16(afr, bfr, acc[m], 0,0,0);
    }
  }
  #pragma unroll
  for (int m = 0; m < 4; ++m)
    #pragma unroll
    for (int r = 0; r < 4; ++r) {
      int b = m*16 + q*4 + r, col = n0 + p;
      float v = acc[m][r];
      if (bias && col < nbias) v += bias[col];
      if (mode == 2) v = tanhfast(v);
      if (mode == 0) ((float*)C)[(size_t)b*ldc + col] = v;
      else ((unsigned short*)C)[(size_t)b*ldc + col] = f2bf(v);
    }
}

// ---------------- attention score: score[t,b] = sum_n v[n]*tanh(enc+q) ------
__global__ void __launch_bounds__(256) attn_score(
  const unsigned short* __restrict__ encp,  // [T*64][LDE] bf16 (incl attn_b)
  const float* __restrict__ qv,             // [64][LDE]
  const float* __restrict__ av,             // attn_v [1032]
  float* __restrict__ score)                // [T][64]
{
  int t = blockIdx.x;
  int w = threadIdx.x>>6, lane = threadIdx.x&63;
  float vv[17];
  #pragma unroll
  for (int i = 0; i < 17; ++i) { int n = i*64+lane; vv[i] = (n < 1032) ? av[n] : 0.f; }
  const unsigned short* erow = encp + (size_t)t*BB*LDE;
  for (int bb = 0; bb < 16; ++bb) {
    int b = w*16 + bb;
    const unsigned short* e = erow + (size_t)b*LDE;
    const float* qb = qv + (size_t)b*LDE;
    float s = 0.f;
    #pragma unroll
    for (int i = 0; i < 17; ++i) {
      int n = i*64 + lane;
      s += vv[i] * tanhfast(bf2f(e[n]) + qb[n]);
    }
    #pragma unroll
    for (int off = 32; off; off >>= 1) s += __shfl_xor(s, off);
    if (lane == 0) score[(size_t)t*BB + b] = s;
  }
}

// ---------------- softmax over T + context; writes context into Xc ---------
__global__ void __launch_bounds__(256) attn_ctx(
  const float* __restrict__ score,          // [T][64]
  const unsigned short* __restrict__ outenc,// [T*64][LD2]
  unsigned short* __restrict__ Xc)          // [64][2176], context at cols 1088+
{
  __shared__ float aw[512];
  __shared__ float red[4];
  int tid = threadIdx.x, w = tid>>6, lane = tid&63;
  int b = blockIdx.x >> 1, half = blockIdx.x & 1;
  float s0 = score[(size_t)tid*BB + b];
  float s1 = score[(size_t)(tid+256)*BB + b];
  float m = fmaxf(s0, s1);
  #pragma unroll
  for (int off = 32; off; off >>= 1) m = fmaxf(m, __shfl_xor(m, off));
  if (lane == 0) red[w] = m;
  __syncthreads();
  m = fmaxf(fmaxf(red[0], red[1]), fmaxf(red[2], red[3]));
  __syncthreads();
  float e0 = __expf(s0 - m), e1 = __expf(s1 - m);
  aw[tid] = e0; aw[tid+256] = e1;
  float ss = e0 + e1;
  #pragma unroll
  for (int off = 32; off; off >>= 1) ss += __shfl_xor(ss, off);
  if (lane == 0) red[w] = ss;
  __syncthreads();
  float inv = 1.f / (red[0]+red[1]+red[2]+red[3]);
  float acc0 = 0.f, acc1 = 0.f, acc2 = 0.f;
  const unsigned short* base = outenc + (size_t)b*LD2 + half*HP;
  for (int t = 0; t < 512; ++t) {
    float a_ = aw[t];
    const unsigned short* orow = base + (size_t)t*BB*LD2;
    acc0 += a_ * bf2f(orow[tid]);
    acc1 += a_ * bf2f(orow[tid+256]);
    if (tid < 32) acc2 += a_ * bf2f(orow[tid+512]);
  }
  unsigned short* dst = Xc + (size_t)b*2176 + 1088 + half*HP;
  dst[tid]      = f2bf(acc0*inv);
  dst[tid+256]  = f2bf(acc1*inv);
  if (tid < 32) dst[tid+512] = f2bf(acc2*inv);
}

// ---------------- cross-entropy for one decoder step ------------------------
__global__ void ce_k(const float* __restrict__ logits, // [64][64] f32, 20 valid
                     const int* __restrict__ label,    // [64]
                     float* __restrict__ out)
{
  int b = threadIdx.x; // 64 threads = 1 wave
  const float* lr = logits + (size_t)b*64;
  float m = -1e30f;
  for (int n = 0; n < 20; ++n) m = fmaxf(m, lr[n]);
  float s = 0.f;
  for (int n = 0; n < 20; ++n) s += __expf(lr[n] - m);
  int li = label[b];
  float ce = -(lr[li] - m - __logf(s));
  #pragma unroll
  for (int off = 32; off; off >>= 1) ce += __shfl_xor(ce, off);
  if (b == 0) atomicAdd(out, ce * (1.f/64.f));
}

// ---------------- expand: xe = x @ expand_W^T + expand_b --------------------
__global__ void __launch_bounds__(256) expand_k(
  const float* __restrict__ x, const float* __restrict__ eW,
  const float* __restrict__ ebi, unsigned short* __restrict__ xe)
{
  int row = blockIdx.x, j = threadIdx.x;
  const float* xr = x + (size_t)row*4;
  float4 wv = ((const float4*)eW)[j];
  float v = ebi[j] + xr[0]*wv.x + xr[1]*wv.y + xr[2]*wv.z + xr[3]*wv.w;
  xe[(size_t)row*256 + j] = f2bf(v);
}

// ---------------- decoder state init from encoder finals --------------------
__global__ void __launch_bounds__(256) dec_init(
  const unsigned short* __restrict__ encH,  // [2 layer][2 buf][2 dir][64][HP]
  const float* __restrict__ encC,           // [2 layer][2 dir][64][CS]
  unsigned short* __restrict__ decH,        // parity0: [4][64][HP]
  float* __restrict__ decC)                 // [4][64][CS]
{
  int tid = blockIdx.x*256 + threadIdx.x;
  int nth = gridDim.x*256;
  for (int i = tid; i < 4*BB*HP; i += nth) {
    int k = i / (BB*HP), rem = i % (BB*HP);
    decH[i] = encH[((size_t)(k>>1)*4 + (k&1))*BB*HP + rem]; // buf0
  }
  for (int i = tid; i < 4*BB*CS; i += nth) {
    int k = i / (BB*CS), rem = i % (BB*CS);
    decC[i] = encC[((size_t)(k>>1)*2 + (k&1))*BB*CS + rem];
  }
}

// ---------------- weight prepack (f32 -> padded bf16) -----------------------
struct PackA {
  const float *eWi0,*eWh0,*eWi1,*eWh1,*dWi0,*dWh0,*dWi1,*dWh1,*aW,*cW,*oW,*y;
  unsigned short *pEWi0,*pEWh0,*pEWi1,*pEWh1,*pDWi0,*pDWh0,*pDWi1,*pDWh1,
                 *pAW1,*pAW2,*pCW,*pOW,*pY;
};

__global__ void __launch_bounds__(256) pack_k(PackA a){
  int job = blockIdx.y, row = blockIdx.x, tid = threadIdx.x;
  if (job < 16) {
    if (row >= NP) return;
    int d = job & 1, jt = job >> 1;
    int g = row / HP, jj = row % HP; bool vr = jj < Hh; int sr = g*Hh + jj;
    if (jt == 0) {
      unsigned short* dst = a.pEWi0 + ((size_t)d*NP + row)*256;
      const float* s = a.eWi0 + ((size_t)d*FH + sr)*256;
      for (int k = tid; k < 256; k += 256) dst[k] = vr ? f2bf(s[k]) : 0;
    } else if (jt == 1) {
      unsigned short* dst = a.pEWh0 + ((size_t)d*NP + row)*HP;
      const float* s = a.eWh0 + ((size_t)d*FH + sr)*Hh;
      for (int k = tid; k < HP; k += 256) dst[k] = (vr && k < Hh) ? f2bf(s[k]) : 0;
    } else if (jt == 2) {
      unsigned short* dst = a.pEWi1 + ((size_t)d*NP + row)*LD2;
      const float* s = a.eWi1 + ((size_t)d*FH + sr)*1032;
      for (int k = tid; k < LD2; k += 256) {
        int d2 = k/HP, j = k%HP;
        dst[k] = (vr && j < Hh) ? f2bf(s[d2*Hh + j]) : 0;
      }
    } else if (jt == 3) {
      unsigned short* dst = a.pEWh1 + ((size_t)d*NP + row)*HP;
      const float* s = a.eWh1 + ((size_t)d*FH + sr)*Hh;
      for (int k = tid; k < HP; k += 256) dst[k] = (vr && k < Hh) ? f2bf(s[k]) : 0;
    } else if (jt == 4) {
      unsigned short* dst = a.pDWi0 + ((size_t)d*NP + row)*64;
      const float* s = a.dWi0 + ((size_t)d*FH + sr)*20;
      for (int k = tid; k < 64; k += 256) dst[k] = (vr && k < 20) ? f2bf(s[k]) : 0;
    } else if (jt == 5) {
      unsigned short* dst = a.pDWh0 + ((size_t)d*NP + row)*HP;
      const float* s = a.dWh0 + ((size_t)d*FH + sr)*Hh;
      for (int k = tid; k < HP; k += 256) dst[k] = (vr && k < Hh) ? f2bf(s[k]) : 0;
    } else if (jt == 6) {
      unsigned short* dst = a.pDWi1 + ((size_t)d*NP + row)*LD2;
      const float* s = a.dWi1 + ((size_t)d*FH + sr)*1032;
      for (int k = tid; k < LD2; k += 256) {
        int d2 = k/HP, j = k%HP;
        dst[k] = (vr && j < Hh) ? f2bf(s[d2*Hh + j]) : 0;
      }
    } else {
      unsigned short* dst = a.pDWh1 + ((size_t)d*NP + row)*HP;
      const float* s = a.dWh1 + ((size_t)d*FH + sr)*Hh;
      for (int k = tid; k < HP; k += 256) dst[k] = (vr && k < Hh) ? f2bf(s[k]) : 0;
    }
  } else if (job == 16 || job == 17) {
    if (row >= LDE) return;
    bool vr = row < 1032;
    unsigned short* dst = (job == 16 ? a.pAW1 : a.pAW2) + (size_t)row*LD2;
    int off = (job == 16 ? 0 : 1032);
    for (int k = tid; k < LD2; k += 256) {
      int d2 = k/HP, j = k%HP;
      dst[k] = (vr && j < Hh) ? f2bf(a.aW[(size_t)row*FH + off + d2*Hh + j]) : 0;
    }
  } else if (job == 18) {
    if (row >= LDE) return;
    bool vr = row < 1032;
    unsigned short* dst = a.pCW + (size_t)row*2176;
    for (int k = tid; k < 2176; k += 256) {
      int half = k/LD2, r2 = k%LD2, d2 = r2/HP, j = r2%HP;
      dst[k] = (vr && j < Hh) ? f2bf(a.cW[(size_t)row*FH + half*1032 + d2*Hh + j]) : 0;
    }
  } else if (job == 19) {
    if (row >= 64) return;
    unsigned short* dst = a.pOW + (size_t)row*LD2;
    for (int k = tid; k < LD2; k += 256)
      dst[k] = (row < 20 && k < 1032) ? f2bf(a.oW[(size_t)row*1032 + k]) : 0;
  } else {
    if (row >= 1280) return;
    unsigned short* dst = a.pY + (size_t)row*64;
    for (int k = tid; k < 64; k += 256)
      dst[k] = (k < 20) ? f2bf(a.y[(size_t)row*20 + k]) : 0;
  }
}

// ======================== host side =========================================
extern "C" void kernel_launch(void* const* d_in, const int* in_sizes, int n_in,
                              void* d_out, int out_size, void* d_ws, size_t ws_size,
                              hipStream_t stream) {
  const float* x    = (const float*)d_in[0];
  const float* y    = (const float*)d_in[1];
  const int* label  = (const int*)d_in[2];
  const float* expW = (const float*)d_in[3];
  const float* expb = (const float*)d_in[4];
  const float* eWi0 = (const float*)d_in[5];
  const float* eWh0 = (const float*)d_in[6];
  const float* eb0  = (const float*)d_in[7];
  const float* eWi1 = (const float*)d_in[8];
  const float* eWh1 = (const float*)d_in[9];
  const float* eb1  = (const float*)d_in[10];
  const float* dWi0 = (const float*)d_in[11];
  const float* dWh0 = (const float*)d_in[12];
  const float* db0  = (const float*)d_in[13];
  const float* dWi1 = (const float*)d_in[14];
  const float* dWh1 = (const float*)d_in[15];
  const float* db1  = (const float*)d_in[16];
  const float* attW = (const float*)d_in[17];
  const float* attb = (const float*)d_in[18];
  const float* attv = (const float*)d_in[19];
  const float* cW   = (const float*)d_in[20];
  const float* cb   = (const float*)d_in[21];
  const float* oW   = (const float*)d_in[22];
  const float* ob   = (const float*)d_in[23];

  char* base = (char*)d_ws;
  size_t o = 0;
  auto alloc = [&](size_t bytes){ size_t r = o; o = (o + bytes + 255) & ~(size_t)255; return r; };

  // --- zero region (small state) ---
  size_t o_encH  = alloc((size_t)2*2*2*BB*HP*2);
  size_t o_decH  = alloc((size_t)2*4*BB*HP*2);
  size_t o_l0    = alloc((size_t)BB*LD2*2);
  size_t o_Xc    = alloc((size_t)BB*2176*2);
  size_t o_encC  = alloc((size_t)2*2*BB*CS*4);
  size_t o_decC  = alloc((size_t)4*BB*CS*4);
  size_t o_flags = alloc((size_t)2*2*TT*4);   // [layer][dir][T]
  size_t ZB = o;
  // --- rest ---
  size_t o_xe    = alloc((size_t)TT*BB*256*2);
  size_t o_big   = alloc((size_t)TT*BB*LDE*2);   // y0 during enc; encp after
  size_t o_oenc  = alloc((size_t)TT*BB*LD2*2);
  size_t o_pEWi0 = alloc((size_t)2*NP*256*2);
  size_t o_pEWh0 = alloc((size_t)2*NP*HP*2);
  size_t o_pEWi1 = alloc((size_t)2*NP*LD2*2);
  size_t o_pEWh1 = alloc((size_t)2*NP*HP*2);
  size_t o_pDWi0 = alloc((size_t)2*NP*64*2);
  size_t o_pDWh0 = alloc((size_t)2*NP*HP*2);
  size_t o_pDWi1 = alloc((size_t)2*NP*LD2*2);
  size_t o_pDWh1 = alloc((size_t)2*NP*HP*2);
  size_t o_pAW1  = alloc((size_t)LDE*LD2*2);
  size_t o_pAW2  = alloc((size_t)LDE*LD2*2);
  size_t o_pCW   = alloc((size_t)LDE*2176*2);
  size_t o_pOW   = alloc((size_t)64*LD2*2);
  size_t o_pY    = alloc((size_t)1280*64*2);
  size_t o_q     = alloc((size_t)BB*LDE*4);
  size_t o_score = alloc((size_t)TT*BB*4);
  size_t o_co    = alloc((size_t)BB*LD2*2);
  size_t o_log   = alloc((size_t)BB*64*4);
  (void)in_sizes; (void)n_in; (void)out_size;

  if (o > ws_size) return;   // diagnostic guard

  unsigned short* encH = (unsigned short*)(base + o_encH);
  unsigned short* decH = (unsigned short*)(base + o_decH);
  unsigned short* l0   = (unsigned short*)(base + o_l0);
  unsigned short* Xc   = (unsigned short*)(base + o_Xc);
  float* encC = (float*)(base + o_encC);
  float* decC = (float*)(base + o_decC);
  unsigned* flags = (unsigned*)(base + o_flags);
  unsigned short* xe   = (unsigned short*)(base + o_xe);
  unsigned short* y0   = (unsigned short*)(base + o_big);   // [T][64][LD2]
  unsigned short* encp = (unsigned short*)(base + o_big);   // [T][64][LDE] (after y0 dead)
  unsigned short* oenc = (unsigned short*)(base + o_oenc);
  unsigned short* pEWi0 = (unsigned short*)(base + o_pEWi0);
  unsigned short* pEWh0 = (unsigned short*)(base + o_pEWh0);
  unsigned short* pEWi1 = (unsigned short*)(base + o_pEWi1);
  unsigned short* pEWh1 = (unsigned short*)(base + o_pEWh1);
  unsigned short* pDWi0 = (unsigned short*)(base + o_pDWi0);
  unsigned short* pDWh0 = (unsigned short*)(base + o_pDWh0);
  unsigned short* pDWi1 = (unsigned short*)(base + o_pDWi1);
  unsigned short* pDWh1 = (unsigned short*)(base + o_pDWh1);
  unsigned short* pAW1 = (unsigned short*)(base + o_pAW1);
  unsigned short* pAW2 = (unsigned short*)(base + o_pAW2);
  unsigned short* pCW  = (unsigned short*)(base + o_pCW);
  unsigned short* pOW  = (unsigned short*)(base + o_pOW);
  unsigned short* pY   = (unsigned short*)(base + o_pY);
  float* qbuf  = (float*)(base + o_q);
  float* score = (float*)(base + o_score);
  unsigned short* co = (unsigned short*)(base + o_co);
  float* logits = (float*)(base + o_log);

  hipMemsetAsync(d_ws, 0, ZB, stream);
  hipMemsetAsync(d_out, 0, sizeof(float), stream);

  PackA pa;
  pa.eWi0 = eWi0; pa.eWh0 = eWh0; pa.eWi1 = eWi1; pa.eWh1 = eWh1;
  pa.dWi0 = dWi0; pa.dWh0 = dWh0; pa.dWi1 = dWi1; pa.dWh1 = dWh1;
  pa.aW = attW; pa.cW = cW; pa.oW = oW; pa.y = y;
  pa.pEWi0 = pEWi0; pa.pEWh0 = pEWh0; pa.pEWi1 = pEWi1; pa.pEWh1 = pEWh1;
  pa.pDWi0 = pDWi0; pa.pDWh0 = pDWh0; pa.pDWi1 = pDWi1; pa.pDWh1 = pDWh1;
  pa.pAW1 = pAW1; pa.pAW2 = pAW2; pa.pCW = pCW; pa.pOW = pOW; pa.pY = pY;
  pack_k<<<dim3(NP, 21), 256, 0, stream>>>(pa);

  expand_k<<<TT*BB, 256, 0, stream>>>(x, expW, expb, xe);

  // encoder layer 0 (fused input GEMM + recurrence, flag-synced)
  enc_rnn<<<66, 256, 0, stream>>>(pEWi0, 256, 256, xe, 256,
      pEWh0, eb0, y0, encH, encC, flags);
  // encoder layer 1
  enc_rnn<<<66, 256, 0, stream>>>(pEWi1, LD2, LD2, y0, LD2,
      pEWh1, eb1, oenc, encH + (size_t)2*2*BB*HP, encC + (size_t)2*BB*CS,
      flags + 2*TT);

  dec_init<<<64, 256, 0, stream>>>(encH, encC, decH, decC);

  // enc_part = outenc @ attn_W[:,1032:]^T + attn_b   (y0 dead -> encp aliases it)
  gemm_bt<<<dim3(256, 9), 256, 0, stream>>>(
      oenc, LD2, pAW2, LD2, encp, LDE, LD2, attb, 1032);

  const size_t DHB = (size_t)4*BB*HP;
  for (int s = 0; s < 20; ++s) {
    int p = s & 1, p2 = p ^ 1;
    dec_cell<<<66, 256, 0, stream>>>(
      pY + (size_t)s*64*64, 64, 64, decH + (size_t)p*DHB, decH + (size_t)p2*DHB, 0,
      pDWi0, 64, pDWh0, db0, decC, l0, LD2);
    dec_cell<<<66, 256, 0, stream>>>(
      l0, LD2, LD2, decH + (size_t)p*DHB, decH + (size_t)p2*DHB, 2,
      pDWi1, LD2, pDWh1, db1, decC, Xc, 2176);
    gemm64<<<18, 256, 0, stream>>>(Xc, 2176, pAW1, LD2, LD2, nullptr, 0, 0, qbuf, LDE);
    attn_score<<<512, 256, 0, stream>>>(encp, qbuf, attv, score);
    attn_ctx<<<128, 256, 0, stream>>>(score, oenc, Xc);
    gemm64<<<17, 256, 0, stream>>>(Xc, 2176, pCW, 2176, 2176, cb, 1032, 2, co, LD2);
    gemm64<<<1, 256, 0, stream>>>(co, LD2, pOW, LD2, LD2, ob, 20, 0, logits, 64);
    ce_k<<<1, 64, 0, stream>>>(logits, label + (size_t)s*64, (float*)d_out);
  }
}

// Round 4
// 24343.750 us; speedup vs baseline: 1.7298x; 1.0896x over previous
//
#include <hip/hip_runtime.h>
#include <hip/hip_bf16.h>
#include <cstdint>

typedef __attribute__((ext_vector_type(8))) short s8v;
typedef __attribute__((ext_vector_type(4))) float f4v;

#define DEV __device__ __forceinline__

constexpr int Hh  = 516;    // hidden per direction
constexpr int HP  = 544;    // padded hidden (17*32)
constexpr int FH  = 2064;   // 4*H
constexpr int NP  = 2176;   // 4*HP (gate-major padded)
constexpr int TT  = 512;
constexpr int BB  = 64;
constexpr int LD2 = 1088;   // padded 2H (2*HP)
constexpr int LDE = 1152;   // encpart ld (9*128)
constexpr int CS  = 528;    // c-state row stride (f32)
constexpr int XR  = 584;    // LDS stage row stride (shorts)

DEV float bf2f(unsigned short u){ return __builtin_bit_cast(float, (unsigned)u<<16); }
DEV unsigned short f2bf(float f){
  unsigned u = __builtin_bit_cast(unsigned, f);
  u += 0x7fffu + ((u>>16)&1u);
  return (unsigned short)(u>>16);
}
DEV float sigf(float x){ return 1.f/(1.f+__expf(-x)); }
DEV float tanhfast(float x){ float e=__expf(2.f*x); return 1.f - 2.f/(e+1.f); }

// ---------------- X1 (input-side) MFMAs, direct global (cached, L2-hot) -----
DEV void cell_x1(f4v (&acc)[4],
                 const unsigned short* __restrict__ X1, int ld1,
                 const unsigned short* __restrict__ W1, int ldw1, int K1,
                 int j0)
{
  const int tid = threadIdx.x;
  const int w = tid>>6, lane = tid&63, p = lane&15, q = lane>>4;
  const unsigned short* wrow = W1 + (size_t)(w*HP + j0 + p)*ldw1 + q*8;
  for (int kk = 0; kk < (K1>>5); ++kk) {
    s8v bfr = *(const s8v*)(wrow + (size_t)kk*32);
    #pragma unroll
    for (int m = 0; m < 4; ++m) {
      s8v afr = *(const s8v*)(X1 + (size_t)(m*16+p)*ld1 + kk*32 + q*8);
      acc[m] = __builtin_amdgcn_mfma_f32_16x16x32_bf16(afr, bfr, acc[m], 0, 0, 0);
    }
  }
}

// ---------------- h-side MFMAs (X2 staged via LDS) + gate epilogue ---------
// X2 is read with REGULAR vector loads (addresses are written-once per call,
// so no stale-cache hazard); AST: write yout via agent-scope atomic stores
// (write-through past L2 -> visible to other XCDs after vmcnt drain).
template<bool AST>
DEV void cell_rest(f4v (&acc)[4],
                   const unsigned short* __restrict__ X2g, int ldx2, // [64][ldx2]
                   const unsigned short* __restrict__ W2,   // [NP][HP]
                   const float* __restrict__ bias,          // [FH] gate-major
                   float* __restrict__ cst,                 // [64][CS]
                   unsigned short* __restrict__ hout,       // optional [64][HP]
                   unsigned short* __restrict__ yout, int ldy, int ycol,
                   int j0)
{
  __shared__ __align__(16) unsigned short Xs[64*XR];
  __shared__ float gbuf[4][64][17];
  const int tid = threadIdx.x;
  const int w = tid>>6, lane = tid&63, p = lane&15, q = lane>>4;

  // ---- stage X2 -> LDS: 17 overlapped dwordx4 loads per thread ----
  {
    int r = tid >> 2, c = tid & 3;
    const char* src = (const char*)X2g + (size_t)r*(ldx2*2) + c*16;
    char* dst = (char*)Xs + (size_t)r*(XR*2) + c*16;
    s8v tmp[17];
    #pragma unroll
    for (int k = 0; k < 17; ++k) tmp[k] = *(const s8v*)(src + (size_t)k*64);
    #pragma unroll
    for (int k = 0; k < 17; ++k) *(s8v*)(dst + k*64) = tmp[k];
  }
  __syncthreads();

  // ---- h-side MFMAs from LDS ----
  {
    const unsigned short* wrow = W2 + (size_t)(w*HP + j0 + p)*HP + q*8;
    #pragma unroll
    for (int kk = 0; kk < HP/32; ++kk) {
      s8v bfr = *(const s8v*)(wrow + kk*32);
      #pragma unroll
      for (int m = 0; m < 4; ++m) {
        s8v afr = *(const s8v*)(Xs + (m*16+p)*XR + kk*32 + q*8);
        acc[m] = __builtin_amdgcn_mfma_f32_16x16x32_bf16(afr, bfr, acc[m], 0, 0, 0);
      }
    }
  }
  // ---- gates -> LDS (padded, conflict-light) ----
  {
    int j = j0 + p;
    float bval = (j < Hh) ? bias[w*Hh + j] : 0.f;
    #pragma unroll
    for (int m = 0; m < 4; ++m)
      #pragma unroll
      for (int r = 0; r < 4; ++r)
        gbuf[w][m*16 + q*4 + r][p] = acc[m][r] + bval;
  }
  __syncthreads();
  // ---- cell nonlinearity + packed state/output writes ----
  {
    int b = tid & 63, j4 = tid >> 6;
    unsigned short hb[4];
    #pragma unroll
    for (int ii = 0; ii < 4; ++ii) {
      int jj = j4*4 + ii, jg = j0 + jj;
      float gi = gbuf[0][b][jj], gf = gbuf[1][b][jj];
      float gg = gbuf[2][b][jj], go = gbuf[3][b][jj];
      bool valid = jg < Hh;
      float c  = valid ? cst[(size_t)b*CS + jg] : 0.f;
      float c2 = sigf(gf)*c + sigf(gi)*tanhfast(gg);
      float h  = sigf(go)*tanhfast(c2);
      if (valid) cst[(size_t)b*CS + jg] = c2;
      hb[ii] = valid ? f2bf(h) : (unsigned short)0;
    }
    unsigned hu0 = (unsigned)hb[0] | ((unsigned)hb[1] << 16);
    unsigned hu1 = (unsigned)hb[2] | ((unsigned)hb[3] << 16);
    unsigned long long yv = (unsigned long long)hu0 | ((unsigned long long)hu1 << 32);
    unsigned long long* yp =
      (unsigned long long*)(yout + (size_t)b*ldy + ycol + j0 + j4*4);
    if (AST)
      __hip_atomic_store(yp, yv, __ATOMIC_RELAXED, __HIP_MEMORY_SCOPE_AGENT);
    else
      *yp = yv;
    if (hout)
      *(unsigned long long*)(hout + (size_t)b*HP + j0 + j4*4) = yv;
  }
  __syncthreads();   // drains vmcnt: all stores retired before flag store
}

// ---------------- persistent encoder recurrent kernel (one layer, fused) ----
__global__ void __launch_bounds__(256) enc_rnn(
  const unsigned short* __restrict__ Wi,   // [2][NP][ldwi]
  int ldwi, int K1,
  const unsigned short* __restrict__ Xseq, // [T][64][ld1]
  int ld1,
  const unsigned short* __restrict__ Wh,   // [2][NP][HP]
  const float* __restrict__ eb,            // [2][FH]
  unsigned short* __restrict__ yout,       // [T][64][LD2] — also the h exchange
  const unsigned short* __restrict__ hz,   // [64][HP] zeros
  float* __restrict__ cst,                 // [2 dir][64][CS]
  unsigned* __restrict__ flags)            // [2 dir][T][64] per-block slots
{
  int d = blockIdx.x / 33, slot = blockIdx.x % 33, j0 = slot * 16;
  const unsigned short* W1 = Wi + (size_t)d*NP*ldwi;
  const unsigned short* W2 = Wh + (size_t)d*NP*HP;
  const float* bias = eb + (size_t)d*FH;
  float* cs = cst + (size_t)d*BB*CS;
  unsigned* flg = flags + (size_t)d*TT*64;
  for (int t = 0; t < TT; ++t) {
    int tf = d ? (TT-1-t) : t;
    f4v acc[4] = {};
    cell_x1(acc, Xseq + (size_t)tf*BB*ld1, ld1, W1, ldwi, K1, j0);
    if (t > 0 && threadIdx.x < 64) {
      const unsigned* f = flg + (size_t)(t-1)*64;
      while (true) {
        unsigned v = (threadIdx.x < 33)
          ? __hip_atomic_load(f + threadIdx.x, __ATOMIC_RELAXED, __HIP_MEMORY_SCOPE_AGENT)
          : 1u;
        if (__all((int)(v != 0))) break;
        __builtin_amdgcn_s_sleep(1);
      }
    }
    __syncthreads();
    const unsigned short* X2g; int ldx2;
    if (t == 0) { X2g = hz; ldx2 = HP; }
    else {
      int tp = d ? (TT - t) : (t - 1);
      X2g = yout + (size_t)tp*BB*LD2 + d*HP; ldx2 = LD2;
    }
    cell_rest<true>(acc, X2g, ldx2, W2, bias, cs, nullptr,
                    yout + (size_t)tf*BB*LD2, LD2, d*HP, j0);
    if (threadIdx.x == 0)
      __hip_atomic_store(flg + (size_t)t*64 + slot, 1u,
                         __ATOMIC_RELAXED, __HIP_MEMORY_SCOPE_AGENT);
  }
}

// ---------------- decoder cell kernel (one step, both dirs) -----------------
__global__ void __launch_bounds__(256) dec_cell(
  const unsigned short* __restrict__ X1, int ld1, int K1,
  const unsigned short* __restrict__ hin_base,   // dec_h[p]  [4][64][HP]
  unsigned short* __restrict__ hout_base,        // dec_h[p2]
  int loff,
  const unsigned short* __restrict__ Wi, int ldwi,
  const unsigned short* __restrict__ Whh,
  const float* __restrict__ dbias,               // [2][FH]
  float* __restrict__ cstates,                   // [4][64][CS]
  unsigned short* __restrict__ yout, int ldy)
{
  int d = blockIdx.x / 33, j0 = (blockIdx.x % 33) * 16;
  f4v acc[4] = {};
  cell_x1(acc, X1, ld1, Wi + (size_t)d*NP*ldwi, ldwi, K1, j0);
  cell_rest<false>(acc,
    hin_base + (size_t)(loff+d)*BB*HP, HP,
    Whh + (size_t)d*NP*HP,
    dbias + (size_t)d*FH,
    cstates + (size_t)(loff+d)*BB*CS,
    hout_base + (size_t)(loff+d)*BB*HP,
    yout, ldy, d*HP, j0);
}

// ---------------- big GEMM: C[M,N](bf16) = A[M,K](bf16) * W[N,K]^T (+bias) --
__global__ void __launch_bounds__(256) gemm_bt(
  const unsigned short* __restrict__ A, int lda,
  const unsigned short* __restrict__ W, int ldw,
  unsigned short* __restrict__ C, int ldc, int K,
  const float* __restrict__ bias, int nbias)
{
  __shared__ __align__(16) unsigned short As[128*72];
  __shared__ __align__(16) unsigned short Ws[128*72];
  int tid = threadIdx.x, w = tid>>6, lane = tid&63, p = lane&15, q = lane>>4;
  int wm = w & 1, wn = w >> 1;
  size_t m0 = (size_t)blockIdx.x * 128;
  int n0 = blockIdx.y * 128;
  f4v acc[4][4] = {};
  for (int k0 = 0; k0 < K; k0 += 64) {
    __syncthreads();
    #pragma unroll
    for (int i = 0; i < 4; ++i) {
      int v = tid + i*256;
      int row = v >> 3, k8 = (v & 7) * 8;
      *(s8v*)(As + row*72 + k8) = *(const s8v*)(A + (m0+row)*lda + k0 + k8);
      *(s8v*)(Ws + row*72 + k8) = *(const s8v*)(W + (size_t)(n0+row)*ldw + k0 + k8);
    }
    __syncthreads();
    #pragma unroll
    for (int kk = 0; kk < 2; ++kk) {
      s8v af[4], bf[4];
      #pragma unroll
      for (int i = 0; i < 4; ++i) {
        af[i] = *(const s8v*)(As + (wm*64 + i*16 + p)*72 + kk*32 + q*8);
        bf[i] = *(const s8v*)(Ws + (wn*64 + i*16 + p)*72 + kk*32 + q*8);
      }
      #pragma unroll
      for (int mt = 0; mt < 4; ++mt)
        #pragma unroll
        for (int nt = 0; nt < 4; ++nt)
          acc[mt][nt] = __builtin_amdgcn_mfma_f32_16x16x32_bf16(af[mt], bf[nt], acc[mt][nt], 0,0,0);
    }
  }
  #pragma unroll
  for (int mt = 0; mt < 4; ++mt)
    #pragma unroll
    for (int nt = 0; nt < 4; ++nt)
      #pragma unroll
      for (int r = 0; r < 4; ++r) {
        size_t row = m0 + wm*64 + mt*16 + q*4 + r;
        int col = n0 + wn*64 + nt*16 + p;
        float v = acc[mt][nt][r];
        if (bias && col < nbias) v += bias[col];
        C[row*ldc + col] = f2bf(v);
      }
}

// ---------------- small GEMM (M=64): C = A[64,K] * W[N,K]^T ----------------
__global__ void __launch_bounds__(256) gemm64(
  const unsigned short* __restrict__ A, int lda,
  const unsigned short* __restrict__ W, int ldw, int K,
  const float* __restrict__ bias, int nbias, int mode,  // 0:f32 1:bf16 2:bf16+tanh
  void* __restrict__ C, int ldc)
{
  int tid = threadIdx.x, w = tid>>6, lane = tid&63, p = lane&15, q = lane>>4;
  int n0 = blockIdx.x*64 + w*16;
  f4v acc[4] = {};
  const unsigned short* wrow = W + (size_t)(n0+p)*ldw + q*8;
  for (int kk = 0; kk < K/32; ++kk) {
    s8v bfr = *(const s8v*)(wrow + kk*32);
    #pragma unroll
    for (int m = 0; m < 4; ++m) {
      s8v afr = *(const s8v*)(A + (size_t)(m*16+p)*lda + kk*32 + q*8);
      acc[m] = __builtin_amdgcn_mfma_f32_16x16x32_bf16(afr, bfr, acc[m], 0,0,0);
    }
  }
  #pragma unroll
  for (int m = 0; m < 4; ++m)
    #pragma unroll
    for (int r = 0; r < 4; ++r) {
      int b = m*16 + q*4 + r, col = n0 + p;
      float v = acc[m][r];
      if (bias && col < nbias) v += bias[col];
      if (mode == 2) v = tanhfast(v);
      if (mode == 0) ((float*)C)[(size_t)b*ldc + col] = v;
      else ((unsigned short*)C)[(size_t)b*ldc + col] = f2bf(v);
    }
}

// ---------------- attention score: score[t,b] = sum_n v[n]*tanh(enc+q) ------
__global__ void __launch_bounds__(256) attn_score(
  const unsigned short* __restrict__ encp,  // [T*64][LDE] bf16 (incl attn_b)
  const float* __restrict__ qv,             // [64][LDE]
  const float* __restrict__ av,             // attn_v [1032]
  float* __restrict__ score)                // [T][64]
{
  int t = blockIdx.x;
  int w = threadIdx.x>>6, lane = threadIdx.x&63;
  float vv[17];
  #pragma unroll
  for (int i = 0; i < 17; ++i) { int n = i*64+lane; vv[i] = (n < 1032) ? av[n] : 0.f; }
  const unsigned short* erow = encp + (size_t)t*BB*LDE;
  for (int bb = 0; bb < 16; ++bb) {
    int b = w*16 + bb;
    const unsigned short* e = erow + (size_t)b*LDE;
    const float* qb = qv + (size_t)b*LDE;
    float s = 0.f;
    #pragma unroll
    for (int i = 0; i < 17; ++i) {
      int n = i*64 + lane;
      s += vv[i] * tanhfast(bf2f(e[n]) + qb[n]);
    }
    #pragma unroll
    for (int off = 32; off; off >>= 1) s += __shfl_xor(s, off);
    if (lane == 0) score[(size_t)t*BB + b] = s;
  }
}

// ---------------- softmax over T + context; writes context into Xc ---------
__global__ void __launch_bounds__(256) attn_ctx(
  const float* __restrict__ score,          // [T][64]
  const unsigned short* __restrict__ outenc,// [T*64][LD2]
  unsigned short* __restrict__ Xc)          // [64][2176], context at cols 1088+
{
  __shared__ float aw[512];
  __shared__ float red[4];
  int tid = threadIdx.x, w = tid>>6, lane = tid&63;
  int b = blockIdx.x >> 1, half = blockIdx.x & 1;
  float s0 = score[(size_t)tid*BB + b];
  float s1 = score[(size_t)(tid+256)*BB + b];
  float m = fmaxf(s0, s1);
  #pragma unroll
  for (int off = 32; off; off >>= 1) m = fmaxf(m, __shfl_xor(m, off));
  if (lane == 0) red[w] = m;
  __syncthreads();
  m = fmaxf(fmaxf(red[0], red[1]), fmaxf(red[2], red[3]));
  __syncthreads();
  float e0 = __expf(s0 - m), e1 = __expf(s1 - m);
  aw[tid] = e0; aw[tid+256] = e1;
  float ss = e0 + e1;
  #pragma unroll
  for (int off = 32; off; off >>= 1) ss += __shfl_xor(ss, off);
  if (lane == 0) red[w] = ss;
  __syncthreads();
  float inv = 1.f / (red[0]+red[1]+red[2]+red[3]);
  float acc0 = 0.f, acc1 = 0.f, acc2 = 0.f;
  const unsigned short* base = outenc + (size_t)b*LD2 + half*HP;
  for (int t = 0; t < 512; ++t) {
    float a_ = aw[t];
    const unsigned short* orow = base + (size_t)t*BB*LD2;
    acc0 += a_ * bf2f(orow[tid]);
    acc1 += a_ * bf2f(orow[tid+256]);
    if (tid < 32) acc2 += a_ * bf2f(orow[tid+512]);
  }
  unsigned short* dst = Xc + (size_t)b*2176 + 1088 + half*HP;
  dst[tid]      = f2bf(acc0*inv);
  dst[tid+256]  = f2bf(acc1*inv);
  if (tid < 32) dst[tid+512] = f2bf(acc2*inv);
}

// ---------------- cross-entropy for one decoder step ------------------------
__global__ void ce_k(const float* __restrict__ logits, // [64][64] f32, 20 valid
                     const int* __restrict__ label,    // [64]
                     float* __restrict__ out)
{
  int b = threadIdx.x; // 64 threads = 1 wave
  const float* lr = logits + (size_t)b*64;
  float m = -1e30f;
  for (int n = 0; n < 20; ++n) m = fmaxf(m, lr[n]);
  float s = 0.f;
  for (int n = 0; n < 20; ++n) s += __expf(lr[n] - m);
  int li = label[b];
  float ce = -(lr[li] - m - __logf(s));
  #pragma unroll
  for (int off = 32; off; off >>= 1) ce += __shfl_xor(ce, off);
  if (b == 0) atomicAdd(out, ce * (1.f/64.f));
}

// ---------------- expand: xe = x @ expand_W^T + expand_b --------------------
__global__ void __launch_bounds__(256) expand_k(
  const float* __restrict__ x, const float* __restrict__ eW,
  const float* __restrict__ ebi, unsigned short* __restrict__ xe)
{
  int row = blockIdx.x, j = threadIdx.x;
  const float* xr = x + (size_t)row*4;
  float4 wv = ((const float4*)eW)[j];
  float v = ebi[j] + xr[0]*wv.x + xr[1]*wv.y + xr[2]*wv.z + xr[3]*wv.w;
  xe[(size_t)row*256 + j] = f2bf(v);
}

// ---------------- decoder state init from encoder finals --------------------
__global__ void __launch_bounds__(256) dec_init(
  const unsigned short* __restrict__ y0,    // [T][64][LD2] layer0 outputs
  const unsigned short* __restrict__ oenc,  // [T][64][LD2] layer1 outputs
  const float* __restrict__ encC,           // [2 layer][2 dir][64][CS]
  unsigned short* __restrict__ decH,        // parity0: [4][64][HP]
  float* __restrict__ decC)                 // [4][64][CS]
{
  int tid = blockIdx.x*256 + threadIdx.x;
  int nth = gridDim.x*256;
  for (int i = tid; i < 4*BB*HP; i += nth) {
    int k = i / (BB*HP), rem = i % (BB*HP);
    int b = rem / HP, j = rem % HP;
    const unsigned short* src = (k < 2) ? y0 : oenc;
    int t = (k & 1) ? 0 : (TT-1);   // fwd final at T-1, bwd final at t=0
    decH[i] = src[(size_t)t*BB*LD2 + (size_t)b*LD2 + (k&1)*HP + j];
  }
  for (int i = tid; i < 4*BB*CS; i += nth) {
    int k = i / (BB*CS), rem = i % (BB*CS);
    decC[i] = encC[((size_t)(k>>1)*2 + (k&1))*BB*CS + rem];
  }
}

// ---------------- weight prepack (f32 -> padded bf16) -----------------------
struct PackA {
  const float *eWi0,*eWh0,*eWi1,*eWh1,*dWi0,*dWh0,*dWi1,*dWh1,*aW,*cW,*oW,*y;
  unsigned short *pEWi0,*pEWh0,*pEWi1,*pEWh1,*pDWi0,*pDWh0,*pDWi1,*pDWh1,
                 *pAW1,*pAW2,*pCW,*pOW,*pY;
};

__global__ void __launch_bounds__(256) pack_k(PackA a){
  int job = blockIdx.y, row = blockIdx.x, tid = threadIdx.x;
  if (job < 16) {
    if (row >= NP) return;
    int d = job & 1, jt = job >> 1;
    int g = row / HP, jj = row % HP; bool vr = jj < Hh; int sr = g*Hh + jj;
    if (jt == 0) {
      unsigned short* dst = a.pEWi0 + ((size_t)d*NP + row)*256;
      const float* s = a.eWi0 + ((size_t)d*FH + sr)*256;
      for (int k = tid; k < 256; k += 256) dst[k] = vr ? f2bf(s[k]) : 0;
    } else if (jt == 1) {
      unsigned short* dst = a.pEWh0 + ((size_t)d*NP + row)*HP;
      const float* s = a.eWh0 + ((size_t)d*FH + sr)*Hh;
      for (int k = tid; k < HP; k += 256) dst[k] = (vr && k < Hh) ? f2bf(s[k]) : 0;
    } else if (jt == 2) {
      unsigned short* dst = a.pEWi1 + ((size_t)d*NP + row)*LD2;
      const float* s = a.eWi1 + ((size_t)d*FH + sr)*1032;
      for (int k = tid; k < LD2; k += 256) {
        int d2 = k/HP, j = k%HP;
        dst[k] = (vr && j < Hh) ? f2bf(s[d2*Hh + j]) : 0;
      }
    } else if (jt == 3) {
      unsigned short* dst = a.pEWh1 + ((size_t)d*NP + row)*HP;
      const float* s = a.eWh1 + ((size_t)d*FH + sr)*Hh;
      for (int k = tid; k < HP; k += 256) dst[k] = (vr && k < Hh) ? f2bf(s[k]) : 0;
    } else if (jt == 4) {
      unsigned short* dst = a.pDWi0 + ((size_t)d*NP + row)*64;
      const float* s = a.dWi0 + ((size_t)d*FH + sr)*20;
      for (int k = tid; k < 64; k += 256) dst[k] = (vr && k < 20) ? f2bf(s[k]) : 0;
    } else if (jt == 5) {
      unsigned short* dst = a.pDWh0 + ((size_t)d*NP + row)*HP;
      const float* s = a.dWh0 + ((size_t)d*FH + sr)*Hh;
      for (int k = tid; k < HP; k += 256) dst[k] = (vr && k < Hh) ? f2bf(s[k]) : 0;
    } else if (jt == 6) {
      unsigned short* dst = a.pDWi1 + ((size_t)d*NP + row)*LD2;
      const float* s = a.dWi1 + ((size_t)d*FH + sr)*1032;
      for (int k = tid; k < LD2; k += 256) {
        int d2 = k/HP, j = k%HP;
        dst[k] = (vr && j < Hh) ? f2bf(s[d2*Hh + j]) : 0;
      }
    } else {
      unsigned short* dst = a.pDWh1 + ((size_t)d*NP + row)*HP;
      const float* s = a.dWh1 + ((size_t)d*FH + sr)*Hh;
      for (int k = tid; k < HP; k += 256) dst[k] = (vr && k < Hh) ? f2bf(s[k]) : 0;
    }
  } else if (job == 16 || job == 17) {
    if (row >= LDE) return;
    bool vr = row < 1032;
    unsigned short* dst = (job == 16 ? a.pAW1 : a.pAW2) + (size_t)row*LD2;
    int off = (job == 16 ? 0 : 1032);
    for (int k = tid; k < LD2; k += 256) {
      int d2 = k/HP, j = k%HP;
      dst[k] = (vr && j < Hh) ? f2bf(a.aW[(size_t)row*FH + off + d2*Hh + j]) : 0;
    }
  } else if (job == 18) {
    if (row >= LDE) return;
    bool vr = row < 1032;
    unsigned short* dst = a.pCW + (size_t)row*2176;
    for (int k = tid; k < 2176; k += 256) {
      int half = k/LD2, r2 = k%LD2, d2 = r2/HP, j = r2%HP;
      dst[k] = (vr && j < Hh) ? f2bf(a.cW[(size_t)row*FH + half*1032 + d2*Hh + j]) : 0;
    }
  } else if (job == 19) {
    if (row >= 64) return;
    unsigned short* dst = a.pOW + (size_t)row*LD2;
    for (int k = tid; k < LD2; k += 256)
      dst[k] = (row < 20 && k < 1032) ? f2bf(a.oW[(size_t)row*1032 + k]) : 0;
  } else {
    if (row >= 1280) return;
    unsigned short* dst = a.pY + (size_t)row*64;
    for (int k = tid; k < 64; k += 256)
      dst[k] = (k < 20) ? f2bf(a.y[(size_t)row*20 + k]) : 0;
  }
}

// ======================== host side =========================================
extern "C" void kernel_launch(void* const* d_in, const int* in_sizes, int n_in,
                              void* d_out, int out_size, void* d_ws, size_t ws_size,
                              hipStream_t stream) {
  const float* x    = (const float*)d_in[0];
  const float* y    = (const float*)d_in[1];
  const int* label  = (const int*)d_in[2];
  const float* expW = (const float*)d_in[3];
  const float* expb = (const float*)d_in[4];
  const float* eWi0 = (const float*)d_in[5];
  const float* eWh0 = (const float*)d_in[6];
  const float* eb0  = (const float*)d_in[7];
  const float* eWi1 = (const float*)d_in[8];
  const float* eWh1 = (const float*)d_in[9];
  const float* eb1  = (const float*)d_in[10];
  const float* dWi0 = (const float*)d_in[11];
  const float* dWh0 = (const float*)d_in[12];
  const float* db0  = (const float*)d_in[13];
  const float* dWi1 = (const float*)d_in[14];
  const float* dWh1 = (const float*)d_in[15];
  const float* db1  = (const float*)d_in[16];
  const float* attW = (const float*)d_in[17];
  const float* attb = (const float*)d_in[18];
  const float* attv = (const float*)d_in[19];
  const float* cW   = (const float*)d_in[20];
  const float* cb   = (const float*)d_in[21];
  const float* oW   = (const float*)d_in[22];
  const float* ob   = (const float*)d_in[23];

  char* base = (char*)d_ws;
  size_t o = 0;
  auto alloc = [&](size_t bytes){ size_t r = o; o = (o + bytes + 255) & ~(size_t)255; return r; };

  // --- zero region (small state) ---
  size_t o_hz    = alloc((size_t)BB*HP*2);
  size_t o_decH  = alloc((size_t)2*4*BB*HP*2);
  size_t o_l0    = alloc((size_t)BB*LD2*2);
  size_t o_Xc    = alloc((size_t)BB*2176*2);
  size_t o_encC  = alloc((size_t)2*2*BB*CS*4);
  size_t o_decC  = alloc((size_t)4*BB*CS*4);
  size_t o_flags = alloc((size_t)2*2*TT*64*4);   // [layer][dir][T][64]
  size_t ZB = o;
  // --- rest ---
  size_t o_xe    = alloc((size_t)TT*BB*256*2);
  size_t o_big   = alloc((size_t)TT*BB*LDE*2);   // y0 during enc; encp after
  size_t o_oenc  = alloc((size_t)TT*BB*LD2*2);
  size_t o_pEWi0 = alloc((size_t)2*NP*256*2);
  size_t o_pEWh0 = alloc((size_t)2*NP*HP*2);
  size_t o_pEWi1 = alloc((size_t)2*NP*LD2*2);
  size_t o_pEWh1 = alloc((size_t)2*NP*HP*2);
  size_t o_pDWi0 = alloc((size_t)2*NP*64*2);
  size_t o_pDWh0 = alloc((size_t)2*NP*HP*2);
  size_t o_pDWi1 = alloc((size_t)2*NP*LD2*2);
  size_t o_pDWh1 = alloc((size_t)2*NP*HP*2);
  size_t o_pAW1  = alloc((size_t)LDE*LD2*2);
  size_t o_pAW2  = alloc((size_t)LDE*LD2*2);
  size_t o_pCW   = alloc((size_t)LDE*2176*2);
  size_t o_pOW   = alloc((size_t)64*LD2*2);
  size_t o_pY    = alloc((size_t)1280*64*2);
  size_t o_q     = alloc((size_t)BB*LDE*4);
  size_t o_score = alloc((size_t)TT*BB*4);
  size_t o_co    = alloc((size_t)BB*LD2*2);
  size_t o_log   = alloc((size_t)BB*64*4);
  (void)in_sizes; (void)n_in; (void)out_size;

  if (o > ws_size) return;   // diagnostic guard

  unsigned short* hz   = (unsigned short*)(base + o_hz);
  unsigned short* decH = (unsigned short*)(base + o_decH);
  unsigned short* l0   = (unsigned short*)(base + o_l0);
  unsigned short* Xc   = (unsigned short*)(base + o_Xc);
  float* encC = (float*)(base + o_encC);
  float* decC = (float*)(base + o_decC);
  unsigned* flags = (unsigned*)(base + o_flags);
  unsigned short* xe   = (unsigned short*)(base + o_xe);
  unsigned short* y0   = (unsigned short*)(base + o_big);   // [T][64][LD2]
  unsigned short* encp = (unsigned short*)(base + o_big);   // [T][64][LDE] (after y0 dead)
  unsigned short* oenc = (unsigned short*)(base + o_oenc);
  unsigned short* pEWi0 = (unsigned short*)(base + o_pEWi0);
  unsigned short* pEWh0 = (unsigned short*)(base + o_pEWh0);
  unsigned short* pEWi1 = (unsigned short*)(base + o_pEWi1);
  unsigned short* pEWh1 = (unsigned short*)(base + o_pEWh1);
  unsigned short* pDWi0 = (unsigned short*)(base + o_pDWi0);
  unsigned short* pDWh0 = (unsigned short*)(base + o_pDWh0);
  unsigned short* pDWi1 = (unsigned short*)(base + o_pDWi1);
  unsigned short* pDWh1 = (unsigned short*)(base + o_pDWh1);
  unsigned short* pAW1 = (unsigned short*)(base + o_pAW1);
  unsigned short* pAW2 = (unsigned short*)(base + o_pAW2);
  unsigned short* pCW  = (unsigned short*)(base + o_pCW);
  unsigned short* pOW  = (unsigned short*)(base + o_pOW);
  unsigned short* pY   = (unsigned short*)(base + o_pY);
  float* qbuf  = (float*)(base + o_q);
  float* score = (float*)(base + o_score);
  unsigned short* co = (unsigned short*)(base + o_co);
  float* logits = (float*)(base + o_log);

  hipMemsetAsync(d_ws, 0, ZB, stream);
  hipMemsetAsync(d_out, 0, sizeof(float), stream);

  PackA pa;
  pa.eWi0 = eWi0; pa.eWh0 = eWh0; pa.eWi1 = eWi1; pa.eWh1 = eWh1;
  pa.dWi0 = dWi0; pa.dWh0 = dWh0; pa.dWi1 = dWi1; pa.dWh1 = dWh1;
  pa.aW = attW; pa.cW = cW; pa.oW = oW; pa.y = y;
  pa.pEWi0 = pEWi0; pa.pEWh0 = pEWh0; pa.pEWi1 = pEWi1; pa.pEWh1 = pEWh1;
  pa.pDWi0 = pDWi0; pa.pDWh0 = pDWh0; pa.pDWi1 = pDWi1; pa.pDWh1 = pDWh1;
  pa.pAW1 = pAW1; pa.pAW2 = pAW2; pa.pCW = pCW; pa.pOW = pOW; pa.pY = pY;
  pack_k<<<dim3(NP, 21), 256, 0, stream>>>(pa);

  expand_k<<<TT*BB, 256, 0, stream>>>(x, expW, expb, xe);

  // encoder layer 0 (fused input GEMM + recurrence, per-slot flag sync)
  enc_rnn<<<66, 256, 0, stream>>>(pEWi0, 256, 256, xe, 256,
      pEWh0, eb0, y0, hz, encC, flags);
  // encoder layer 1
  enc_rnn<<<66, 256, 0, stream>>>(pEWi1, LD2, LD2, y0, LD2,
      pEWh1, eb1, oenc, hz, encC + (size_t)2*BB*CS, flags + (size_t)2*TT*64);

  dec_init<<<64, 256, 0, stream>>>(y0, oenc, encC, decH, decC);

  // enc_part = outenc @ attn_W[:,1032:]^T + attn_b   (y0 dead -> encp aliases it)
  gemm_bt<<<dim3(256, 9), 256, 0, stream>>>(
      oenc, LD2, pAW2, LD2, encp, LDE, LD2, attb, 1032);

  const size_t DHB = (size_t)4*BB*HP;
  for (int s = 0; s < 20; ++s) {
    int p = s & 1, p2 = p ^ 1;
    dec_cell<<<66, 256, 0, stream>>>(
      pY + (size_t)s*64*64, 64, 64, decH + (size_t)p*DHB, decH + (size_t)p2*DHB, 0,
      pDWi0, 64, pDWh0, db0, decC, l0, LD2);
    dec_cell<<<66, 256, 0, stream>>>(
      l0, LD2, LD2, decH + (size_t)p*DHB, decH + (size_t)p2*DHB, 2,
      pDWi1, LD2, pDWh1, db1, decC, Xc, 2176);
    gemm64<<<18, 256, 0, stream>>>(Xc, 2176, pAW1, LD2, LD2, nullptr, 0, 0, qbuf, LDE);
    attn_score<<<512, 256, 0, stream>>>(encp, qbuf, attv, score);
    attn_ctx<<<128, 256, 0, stream>>>(score, oenc, Xc);
    gemm64<<<17, 256, 0, stream>>>(Xc, 2176, pCW, 2176, 2176, cb, 1032, 2, co, LD2);
    gemm64<<<1, 256, 0, stream>>>(co, LD2, pOW, LD2, LD2, ob, 20, 0, logits, 64);
    ce_k<<<1, 64, 0, stream>>>(logits, label + (size_t)s*64, (float*)d_out);
  }
}